// Round 7
// baseline (286.019 us; speedup 1.0000x reference)
//
#include <hip/hip_runtime.h>
#include <hip/hip_bf16.h>

typedef __bf16 bf16x8 __attribute__((ext_vector_type(8)));
typedef __bf16 bf16x4 __attribute__((ext_vector_type(4)));
typedef float f32x4 __attribute__((ext_vector_type(4)));

__device__ __forceinline__ void gload16(void* lds, const void* g) {
  __builtin_amdgcn_global_load_lds((const __attribute__((address_space(1))) void*)g,
                                   (__attribute__((address_space(3))) void*)lds, 16, 0, 0);
}

// ---------------- weight cast+transpose: in [R][C] fp32 -> out [C][R] bf16 ----------------
__global__ __launch_bounds__(256)
void transpose_cast(const float* __restrict__ in, __bf16* __restrict__ out, int R, int C)
{
  __shared__ __bf16 tile[32][33];
  const int bc = blockIdx.x * 32, br = blockIdx.y * 32;
  const int lx = threadIdx.x & 31, ly = threadIdx.x >> 5;
#pragma unroll
  for (int p = 0; p < 4; ++p)
    tile[ly + p * 8][lx] = (__bf16)in[(size_t)(br + ly + p * 8) * C + bc + lx];
  __syncthreads();
#pragma unroll
  for (int p = 0; p < 4; ++p)
    out[(size_t)(bc + ly + p * 8) * R + br + lx] = tile[lx][ly + p * 8];
}

// ---------------- V transpose (bf16): qkv [B*S][3072] -> vtg [BH][64][2048] ----------------
__global__ __launch_bounds__(256)
void vtrans(const __bf16* __restrict__ qkv, __bf16* __restrict__ vtg)
{
  __shared__ __bf16 tile[32][33];
  const int sx = blockIdx.x * 32;
  const int dy = blockIdx.y * 32;
  const int z = blockIdx.z;
  const int b = z >> 4, h = z & 15;
  const int lx = threadIdx.x & 31, ly = threadIdx.x >> 5;
  const __bf16* src = qkv + (size_t)b * 2048 * 3072 + 2048 + h * 64;
#pragma unroll
  for (int p = 0; p < 4; ++p)
    tile[ly + p * 8][lx] = src[(size_t)(sx + ly + p * 8) * 3072 + dy + lx];
  __syncthreads();
  __bf16* dst = vtg + (size_t)z * 64 * 2048;
#pragma unroll
  for (int p = 0; p < 4; ++p)
    dst[(size_t)(dy + ly + p * 8) * 2048 + sx + lx] = tile[lx][ly + p * 8];
}

// ---------------- elementwise cast fp32 -> bf16 ----------------
__global__ __launch_bounds__(256)
void cast_bf16(const float* __restrict__ in, __bf16* __restrict__ out)
{
  const int i = (blockIdx.x * 256 + threadIdx.x) * 4;
  float4 v = *(const float4*)(in + i);
  out[i] = (__bf16)v.x; out[i + 1] = (__bf16)v.y;
  out[i + 2] = (__bf16)v.z; out[i + 3] = (__bf16)v.w;
}

// ================= deep-pipelined MFMA GEMM (counted vmcnt, quad-buffer BK=32) ============
// 512 threads = 8 waves (2M x 4N). Tile BM x 256. 4 LDS buffers of one K-subtile (BK=32).
// Iter t: stage subtile t+3 -> buf[(t+3)&3] (clamped restage at tail keeps vmcnt uniform),
// vmcnt(3R) [3 subtiles in flight, never drained], barrier, 2 MFMA phases, lgkmcnt(0),
// barrier (retire buf before iter t+1's stage overwrites it).
// Safety: buf[(t+3)&3] was last read in iter t-1, whose reads drained (lgkmcnt(0)) before
// the end-barrier; this iter's STAGE is issued after that barrier in program order.
template<int BM, bool OUTBF16, bool RELU, bool RESID, bool SPLIT>
__global__ __launch_bounds__(512, 2)
void gemm8(const __bf16* __restrict__ A, const __bf16* __restrict__ Bt,
           const float* __restrict__ bias, const float* __restrict__ resid,
           void* __restrict__ C0v, void* __restrict__ C1v,
           int M, int N, int Kfull, int Ksub)
{
  constexpr int FM = BM / 32;        // M-fragments per wave (8 or 4)
  constexpr int RA = BM / 128;       // A stage rounds per subtile (2 or 1)
  __shared__ __align__(16) __bf16 As[4][BM * 32];
  __shared__ __align__(16) __bf16 Bs[4][256 * 32];
  const int tid = threadIdx.x, wave = tid >> 6, lane = tid & 63;
  const int g = lane >> 4, l16 = lane & 15;
  const int wr = wave >> 2, wc = wave & 3;
  const int row0 = blockIdx.x * BM, col0 = blockIdx.y * 256;
  const int z = SPLIT ? blockIdx.z : 0;
  const __bf16* Az = A + (size_t)z * Ksub;
  const __bf16* Bz = Bt + (size_t)z * Ksub;
  const int nk = Ksub >> 5;
  const int wbase = wave * 64;
  f32x4 acc[FM][4] = {};

  // swizzle: physical chunk p (16B) of row r holds logical chunk p ^ ((r>>1)&3).
  // With 16-lane HW phasing this gives 2 lanes/bank on all b128 reads (free),
  // matching the measured zero-conflict pattern of the BK=64 kernel.
  auto STAGE = [&](int buf, int ks) {
    const int k0 = ks << 5;
#pragma unroll
    for (int r = 0; r < RA; ++r) {
      const int seg = r * 512 + tid;
      const int row = seg >> 2;
      const int src = ((seg & 3) ^ ((row >> 1) & 3)) << 3;
      gload16(&As[buf][(size_t)(r * 512 + wbase) * 8],
              &Az[(size_t)(row0 + row) * Kfull + k0 + src]);
    }
#pragma unroll
    for (int r = 0; r < 2; ++r) {
      const int seg = r * 512 + tid;
      const int row = seg >> 2;
      const int src = ((seg & 3) ^ ((row >> 1) & 3)) << 3;
      gload16(&Bs[buf][(size_t)(r * 512 + wbase) * 8],
              &Bz[(size_t)(col0 + row) * Kfull + k0 + src]);
    }
  };

  STAGE(0, 0); STAGE(1, 1); STAGE(2, 2);

#pragma unroll 1
  for (int t = 0; t < nk; ++t) {
    const int cur = t & 3;
    const int nxt = (t + 3 < nk) ? (t + 3) : (nk - 1);   // tail: dummy restage, count uniform
    STAGE((t + 3) & 3, nxt);
    if constexpr (BM == 256) asm volatile("s_waitcnt vmcnt(12)" ::: "memory");
    else                     asm volatile("s_waitcnt vmcnt(9)" ::: "memory");
    __builtin_amdgcn_s_barrier();
    asm volatile("" ::: "memory");

    bf16x8 bfr[4];
#pragma unroll
    for (int fn = 0; fn < 4; ++fn) {
      const int row = wc * 64 + fn * 16 + l16;
      bfr[fn] = *(const bf16x8*)&Bs[cur][row * 32 + ((g ^ ((row >> 1) & 3)) << 3)];
    }
    bf16x8 af[FM / 2];
#pragma unroll
    for (int fm = 0; fm < FM / 2; ++fm) {
      const int row = wr * (BM / 2) + fm * 16 + l16;
      af[fm] = *(const bf16x8*)&As[cur][row * 32 + ((g ^ ((row >> 1) & 3)) << 3)];
    }
    __builtin_amdgcn_s_setprio(1);
#pragma unroll
    for (int fm = 0; fm < FM / 2; ++fm)
#pragma unroll
      for (int fn = 0; fn < 4; ++fn)
        acc[fm][fn] = __builtin_amdgcn_mfma_f32_16x16x32_bf16(af[fm], bfr[fn], acc[fm][fn], 0, 0, 0);
    __builtin_amdgcn_s_setprio(0);

    bf16x8 af2[FM / 2];
#pragma unroll
    for (int fm = 0; fm < FM / 2; ++fm) {
      const int row = wr * (BM / 2) + (FM / 2 + fm) * 16 + l16;
      af2[fm] = *(const bf16x8*)&As[cur][row * 32 + ((g ^ ((row >> 1) & 3)) << 3)];
    }
    __builtin_amdgcn_s_setprio(1);
#pragma unroll
    for (int fm = 0; fm < FM / 2; ++fm)
#pragma unroll
      for (int fn = 0; fn < 4; ++fn)
        acc[FM / 2 + fm][fn] = __builtin_amdgcn_mfma_f32_16x16x32_bf16(af2[fm], bfr[fn], acc[FM / 2 + fm][fn], 0, 0, 0);
    __builtin_amdgcn_s_setprio(0);

    asm volatile("s_waitcnt lgkmcnt(0)" ::: "memory");   // my DS reads drained
    __builtin_amdgcn_s_barrier();                        // all waves done with buf[cur]
    asm volatile("" ::: "memory");
  }

  // epilogue
#pragma unroll
  for (int fn = 0; fn < 4; ++fn) {
    const int col = col0 + wc * 64 + fn * 16 + l16;
    float bv = 0.f;
    if (!SPLIT || z == 0) bv = bias[col];
#pragma unroll
    for (int fm = 0; fm < FM; ++fm) {
      const int rbase = row0 + wr * (BM / 2) + fm * 16 + g * 4;
#pragma unroll
      for (int j = 0; j < 4; ++j) {
        float v = acc[fm][fn][j] + bv;
        if (RESID) { if (!SPLIT || z == 0) v += resid[(size_t)(rbase + j) * N + col]; }
        if (RELU) v = fmaxf(v, 0.f);
        if (SPLIT) {
          float* C = z ? (float*)C1v : (float*)C0v;
          C[(size_t)(rbase + j) * N + col] = v;
        } else if (OUTBF16) {
          ((__bf16*)C0v)[(size_t)(rbase + j) * N + col] = (__bf16)v;
        } else {
          ((float*)C0v)[(size_t)(rbase + j) * N + col] = v;
        }
      }
    }
  }
}

// ---------------- flash attention (causal), swapped-QK^T, no-max softmax, paired tiles ----
// grid (32 bh, 16 pairs); block (bh,p) does q-tiles p and 31-p => uniform 33 kv-tiles.
__global__ __launch_bounds__(256)
void attn_fwd(const __bf16* __restrict__ qkv, const __bf16* __restrict__ vtg,
              __bf16* __restrict__ ctx)
{
  constexpr int S = 2048, H = 1024, W3 = 3 * H;
  __shared__ __bf16 Ks[2][64 * 64];
  __shared__ __bf16 Vt[2][64 * 64];
  __shared__ __bf16 Ps[4][16 * 64];
  const int tid = threadIdx.x, wave = tid >> 6, lane = tid & 63;
  const int g = lane >> 4, l16 = lane & 15;
  const int perm = ((l16 & 7) << 1) | (l16 >> 3);   // 4-bit row key for 8B-granular swizzle
  const int bh = blockIdx.x;
  const int b = bh >> 4, h = bh & 15;
  const size_t base = (size_t)b * S * W3;
  const __bf16* Qg = qkv + base;
  const __bf16* Kg = qkv + base + H;
  const __bf16* Vg = vtg + (size_t)bh * 64 * S;   // [d][s]

  auto STAGE_KV = [&](int buf, int kv0) {
#pragma unroll
    for (int r = 0; r < 2; ++r) {
      const int seg = r * 256 + tid;
      const int row = seg >> 3;
      const int ko = ((seg & 7) ^ (row & 7)) * 8;
      gload16(&Ks[buf][(r * 256 + wave * 64) * 8], &Kg[(size_t)(kv0 + row) * W3 + h * 64 + ko]);
      gload16(&Vt[buf][(r * 256 + wave * 64) * 8], &Vg[(size_t)row * S + kv0 + ko]);
    }
  };

#pragma unroll 1
  for (int half = 0; half < 2; ++half) {
    const int qi = half ? (31 - blockIdx.y) : blockIdx.y;
    const int q0 = qi * 64;
    const int qrow = q0 + wave * 16 + l16;
    bf16x8 qa[2];
#pragma unroll
    for (int kk = 0; kk < 2; ++kk)
      qa[kk] = *(const bf16x8*)&Qg[(size_t)qrow * W3 + h * 64 + kk * 32 + g * 8];

    f32x4 o[4] = {};
    float lsum = 0.f;
    const int nT = qi + 1;

    STAGE_KV(0, 0);
    __syncthreads();
    int cur = 0;

    for (int t = 0; t < nT; ++t) {
      const int kv0 = t * 64;
      if (t + 1 < nT) STAGE_KV(cur ^ 1, kv0 + 64);

      // S^T = K @ Q^T : lane holds q = qrow (col l16), k-rows kv0 + n*16 + g*4 + r
      f32x4 s[4] = {};
      __builtin_amdgcn_s_setprio(1);
#pragma unroll
      for (int kk = 0; kk < 2; ++kk) {
        bf16x8 kb[4];
#pragma unroll
        for (int n = 0; n < 4; ++n) {
          const int row = n * 16 + l16;
          kb[n] = *(const bf16x8*)&Ks[cur][row * 64 + ((kk * 32 + g * 8) ^ ((row & 7) << 3))];
        }
#pragma unroll
        for (int n = 0; n < 4; ++n)
          s[n] = __builtin_amdgcn_mfma_f32_16x16x32_bf16(kb[n], qa[kk], s[n], 0, 0, 0);
      }
      __builtin_amdgcn_s_setprio(0);

      // softmax-lite: p = exp2(s*log2e/8); mask only diagonal tile; deferred denominator.
      const bool diag = (t == nT - 1);
#pragma unroll
      for (int n = 0; n < 4; ++n) {
        float lp[4];
#pragma unroll
        for (int r = 0; r < 4; ++r) {
          const int ka = kv0 + n * 16 + g * 4 + r;
          float p = exp2f(s[n][r] * 0.18033688f);
          if (diag && ka > qrow) p = 0.f;
          lp[r] = p;
          lsum += p;
        }
        bf16x4 pk;
        pk[0] = (__bf16)lp[0]; pk[1] = (__bf16)lp[1];
        pk[2] = (__bf16)lp[2]; pk[3] = (__bf16)lp[3];
        // 8B-granular swizzle: h4 = 4n+g, slot = h4 ^ perm (conflict-free b64 write)
        *(bf16x4*)&Ps[wave][l16 * 64 + (((4 * n + g) ^ perm) << 2)] = pk;
      }

      // PV: O[q][d] += P[q][k] V[k][d]
      __builtin_amdgcn_s_setprio(1);
#pragma unroll
      for (int kk = 0; kk < 2; ++kk) {
        const int hb = 8 * kk + 2 * g;
        bf16x4 p0 = *(const bf16x4*)&Ps[wave][l16 * 64 + ((hb ^ perm) << 2)];
        bf16x4 p1 = *(const bf16x4*)&Ps[wave][l16 * 64 + (((hb + 1) ^ perm) << 2)];
        bf16x8 pa = __builtin_shufflevector(p0, p1, 0, 1, 2, 3, 4, 5, 6, 7);
        bf16x8 vb[4];
#pragma unroll
        for (int n2 = 0; n2 < 4; ++n2) {
          const int row = n2 * 16 + l16;
          vb[n2] = *(const bf16x8*)&Vt[cur][row * 64 + ((kk * 32 + g * 8) ^ ((row & 7) << 3))];
        }
#pragma unroll
        for (int n2 = 0; n2 < 4; ++n2)
          o[n2] = __builtin_amdgcn_mfma_f32_16x16x32_bf16(pa, vb[n2], o[n2], 0, 0, 0);
      }
      __builtin_amdgcn_s_setprio(0);
      __syncthreads();
      cur ^= 1;
    }

    // denominator: reduce per-lane partials across g-groups; broadcast to o-layout.
    lsum += __shfl_xor(lsum, 16);
    lsum += __shfl_xor(lsum, 32);
#pragma unroll
    for (int r = 0; r < 4; ++r) {
      const float den = __shfl(lsum, g * 4 + r);
      const float inv = 1.f / den;
      const int qr = q0 + wave * 16 + g * 4 + r;
#pragma unroll
      for (int n2 = 0; n2 < 4; ++n2) {
        const int d = n2 * 16 + l16;
        ctx[(size_t)(b * S + qr) * H + h * 64 + d] = (__bf16)(o[n2][r] * inv);
      }
    }
  }
}

// ---------------- LayerNorm over rows of 1024 (sums two fp32 partial inputs) -------------
template<bool WRITE_BF16, bool TWO_IN>
__global__ __launch_bounds__(256)
void ln_kernel(const float* __restrict__ in, const float* __restrict__ in2,
               const float* __restrict__ gw, const float* __restrict__ bw,
               float* __restrict__ outf, __bf16* __restrict__ outb)
{
  const int row = blockIdx.x, tid = threadIdx.x;
  float4 xv = ((const float4*)(in + (size_t)row * 1024))[tid];
  if (TWO_IN) {
    const float4 yv = ((const float4*)(in2 + (size_t)row * 1024))[tid];
    xv.x += yv.x; xv.y += yv.y; xv.z += yv.z; xv.w += yv.w;
  }
  float s = xv.x + xv.y + xv.z + xv.w;
  float s2 = xv.x * xv.x + xv.y * xv.y + xv.z * xv.z + xv.w * xv.w;
#pragma unroll
  for (int off = 32; off; off >>= 1) { s += __shfl_xor(s, off); s2 += __shfl_xor(s2, off); }
  __shared__ float ps[8];
  if ((tid & 63) == 0) { ps[tid >> 6] = s; ps[4 + (tid >> 6)] = s2; }
  __syncthreads();
  s = ps[0] + ps[1] + ps[2] + ps[3];
  s2 = ps[4] + ps[5] + ps[6] + ps[7];
  const float mean = s * (1.f / 1024.f);
  const float var = s2 * (1.f / 1024.f) - mean * mean;
  const float rs = rsqrtf(var + 1e-5f);
  const float4 gv = ((const float4*)gw)[tid];
  const float4 bv = ((const float4*)bw)[tid];
  float4 y;
  y.x = (xv.x - mean) * rs * gv.x + bv.x;
  y.y = (xv.y - mean) * rs * gv.y + bv.y;
  y.z = (xv.z - mean) * rs * gv.z + bv.z;
  y.w = (xv.w - mean) * rs * gv.w + bv.w;
  ((float4*)(outf + (size_t)row * 1024))[tid] = y;
  if (WRITE_BF16) {
    __bf16* ob = outb + (size_t)row * 1024 + tid * 4;
    ob[0] = (__bf16)y.x; ob[1] = (__bf16)y.y; ob[2] = (__bf16)y.z; ob[3] = (__bf16)y.w;
  }
}

extern "C" void kernel_launch(void* const* d_in, const int* in_sizes, int n_in,
                              void* d_out, int out_size, void* d_ws, size_t ws_size,
                              hipStream_t stream)
{
  (void)in_sizes; (void)n_in; (void)out_size; (void)ws_size;
  const float* x     = (const float*)d_in[0];
  const float* qkv_w = (const float*)d_in[2];
  const float* qkv_b = (const float*)d_in[3];
  const float* out_w = (const float*)d_in[4];
  const float* out_b = (const float*)d_in[5];
  const float* w1    = (const float*)d_in[6];
  const float* b1    = (const float*)d_in[7];
  const float* w2    = (const float*)d_in[8];
  const float* b2    = (const float*)d_in[9];
  const float* ln1g  = (const float*)d_in[10];
  const float* ln1b  = (const float*)d_in[11];
  const float* ln2g  = (const float*)d_in[12];
  const float* ln2b  = (const float*)d_in[13];

  char* ws = (char*)d_ws;
  __bf16* wt_qkv = (__bf16*)(ws + 0);          // [3072][1024]  (dead after QKV gemm)
  __bf16* wt_out = (__bf16*)(ws + 6291456);    // [1024][1024]  (dead after out-proj)
  __bf16* wt_w1  = (__bf16*)(ws + 8388608);    // [4096][1024]  (dead after FFN1)
  __bf16* wt_w2  = (__bf16*)(ws + 16777216);   // [1024][4096]
  __bf16* xb     = (__bf16*)(ws + 25165824);   // x bf16, then ctx
  __bf16* big    = (__bf16*)(ws + 33554432);   // qkv, then pB(out-proj), then h1
  float*  res    = (float*)(ws + 67108864);    // vtg, then pA(out-proj), then qA(FFN2)
  float*  x1f    = (float*)(ws + 83886080);    // ln1 out fp32
  __bf16* x1b    = (__bf16*)(ws + 100663296);  // ln1 out bf16 (dead after FFN1)
  __bf16* vtg    = (__bf16*)res;               // [32][64][2048] (dead after attn)
  float*  pB     = (float*)big;                // out-proj partial z=1 (16MB of big)
  float*  qB     = (float*)ws;                 // FFN2 partial z=1 (over dead wt_qkv/out/w1)

  transpose_cast<<<dim3(96, 32), 256, 0, stream>>>(qkv_w, wt_qkv, 1024, 3072);
  transpose_cast<<<dim3(32, 32), 256, 0, stream>>>(out_w, wt_out, 1024, 1024);
  transpose_cast<<<dim3(128, 32), 256, 0, stream>>>(w1, wt_w1, 1024, 4096);
  transpose_cast<<<dim3(32, 128), 256, 0, stream>>>(w2, wt_w2, 4096, 1024);
  cast_bf16<<<4096, 256, 0, stream>>>(x, xb);

  // QKV: 256x256 tiles, grid 16x12
  gemm8<256, true, false, false, false><<<dim3(16, 12, 1), 512, 0, stream>>>(
      xb, wt_qkv, qkv_b, nullptr, big, nullptr, 4096, 3072, 1024, 1024);
  // V -> V^T per (b,h)
  vtrans<<<dim3(64, 2, 32), 256, 0, stream>>>(big, vtg);
  // attention -> ctx (reuses xb)
  attn_fwd<<<dim3(32, 16), 256, 0, stream>>>(big, vtg, xb);
  // out proj + residual(x), 128x256 split-K=2 -> partials res, pB
  gemm8<128, false, false, true, true><<<dim3(32, 4, 2), 512, 0, stream>>>(
      xb, wt_out, out_b, x, res, pB, 4096, 1024, 1024, 512);
  // LN1 (combines partials) -> x1f fp32, x1b bf16
  ln_kernel<true, true><<<4096, 256, 0, stream>>>(res, pB, ln1g, ln1b, x1f, x1b);
  // FFN1 + ReLU: 256x256 tiles, grid 16x16 -> h1 bf16 (overwrites big)
  gemm8<256, true, true, false, false><<<dim3(16, 16, 1), 512, 0, stream>>>(
      x1b, wt_w1, b1, nullptr, big, nullptr, 4096, 4096, 1024, 1024);
  // FFN2 + residual(x1f), 128x256 split-K=2 -> partials res, qB
  gemm8<128, false, false, true, true><<<dim3(32, 4, 2), 512, 0, stream>>>(
      big, wt_w2, b2, x1f, res, qB, 4096, 1024, 4096, 2048);
  // LN2 (combines partials) -> d_out
  ln_kernel<false, true><<<4096, 256, 0, stream>>>(res, qB, ln2g, ln2b, (float*)d_out, nullptr);
}

// Round 8
// 283.325 us; speedup vs baseline: 1.0095x; 1.0095x over previous
//
#include <hip/hip_runtime.h>
#include <hip/hip_bf16.h>

typedef __bf16 bf16x8 __attribute__((ext_vector_type(8)));
typedef __bf16 bf16x4 __attribute__((ext_vector_type(4)));
typedef float f32x4 __attribute__((ext_vector_type(4)));

__device__ __forceinline__ void gload16(void* lds, const void* g) {
  __builtin_amdgcn_global_load_lds((const __attribute__((address_space(1))) void*)g,
                                   (__attribute__((address_space(3))) void*)lds, 16, 0, 0);
}

// ---------------- weight cast+transpose: in [R][C] fp32 -> out [C][R] bf16 ----------------
__global__ __launch_bounds__(256)
void transpose_cast(const float* __restrict__ in, __bf16* __restrict__ out, int R, int C)
{
  __shared__ __bf16 tile[32][33];
  const int bc = blockIdx.x * 32, br = blockIdx.y * 32;
  const int lx = threadIdx.x & 31, ly = threadIdx.x >> 5;
#pragma unroll
  for (int p = 0; p < 4; ++p)
    tile[ly + p * 8][lx] = (__bf16)in[(size_t)(br + ly + p * 8) * C + bc + lx];
  __syncthreads();
#pragma unroll
  for (int p = 0; p < 4; ++p)
    out[(size_t)(bc + ly + p * 8) * R + br + lx] = tile[lx][ly + p * 8];
}

// ---------------- V transpose (bf16): qkv [B*S][3072] -> vtg [BH][64][2048] ----------------
__global__ __launch_bounds__(256)
void vtrans(const __bf16* __restrict__ qkv, __bf16* __restrict__ vtg)
{
  __shared__ __bf16 tile[32][33];
  const int sx = blockIdx.x * 32;
  const int dy = blockIdx.y * 32;
  const int z = blockIdx.z;
  const int b = z >> 4, h = z & 15;
  const int lx = threadIdx.x & 31, ly = threadIdx.x >> 5;
  const __bf16* src = qkv + (size_t)b * 2048 * 3072 + 2048 + h * 64;
#pragma unroll
  for (int p = 0; p < 4; ++p)
    tile[ly + p * 8][lx] = src[(size_t)(sx + ly + p * 8) * 3072 + dy + lx];
  __syncthreads();
  __bf16* dst = vtg + (size_t)z * 64 * 2048;
#pragma unroll
  for (int p = 0; p < 4; ++p)
    dst[(size_t)(dy + ly + p * 8) * 2048 + sx + lx] = tile[lx][ly + p * 8];
}

// ---------------- elementwise cast fp32 -> bf16 ----------------
__global__ __launch_bounds__(256)
void cast_bf16(const float* __restrict__ in, __bf16* __restrict__ out)
{
  const int i = (blockIdx.x * 256 + threadIdx.x) * 4;
  float4 v = *(const float4*)(in + i);
  out[i] = (__bf16)v.x; out[i + 1] = (__bf16)v.y;
  out[i + 2] = (__bf16)v.z; out[i + 3] = (__bf16)v.w;
}

// ========== 3-buffer counted-vmcnt MFMA GEMM: tile 128x256, BK=64, 8 waves (2Mx4N) =========
// Per iter t: STAGE tile t+2 -> buf[(t+2)%3] (6 gload_lds/thread), 2 ks-phases of
// {8 ds_read_b128 + 16 MFMA}, lgkmcnt(0), vmcnt(6), ONE barrier.
// vmcnt(6): tile t+1's 6 loads drained, tile t+2's 6 in flight (never 0).
// Races: buf[(t+2)%3] != buf[t%3] and != buf[(t+1)%3] (differ mod 3), so staging never
// touches a buffer being read this iter or next; a buffer is re-staged (t+3 into t%3)
// only after the end-of-t barrier, which follows all waves' lgkmcnt(0) on their reads.
template<bool OUTBF16, bool RELU, bool RESID, bool SPLIT>
__global__ __launch_bounds__(512, 2)
void gemm3p(const __bf16* __restrict__ A, const __bf16* __restrict__ Bt,
            const float* __restrict__ bias, const float* __restrict__ resid,
            void* __restrict__ C0v, void* __restrict__ C1v,
            int M, int N, int Kfull, int Ksub)
{
  __shared__ __align__(16) __bf16 As[3][128 * 64];   // 48 KB
  __shared__ __align__(16) __bf16 Bs[3][256 * 64];   // 96 KB  (total 144 KB)
  const int tid = threadIdx.x, wave = tid >> 6, lane = tid & 63;
  const int g = lane >> 4, l16 = lane & 15;
  const int wr = wave >> 2, wc = wave & 3;           // 2M x 4N waves, per-wave 64x64
  const int row0 = blockIdx.x * 128, col0 = blockIdx.y * 256;
  const int z = SPLIT ? blockIdx.z : 0;
  const __bf16* Az = A + (size_t)z * Ksub;
  const __bf16* Bz = Bt + (size_t)z * Ksub;
  const int nk = Ksub >> 6;
  f32x4 acc[4][4] = {};

  // swizzle: physical 16B-chunk p of row r holds logical chunk p ^ (r&7)
  // (pre-swizzled global source; reads land 2 lanes/bank = free, proven r5 pattern)
  auto STAGE = [&](int buf, int kt) {
    const int k0 = kt << 6;
#pragma unroll
    for (int r = 0; r < 2; ++r) {                    // A: 128 rows x 8 chunks
      const int seg = r * 512 + tid;
      const int row = seg >> 3;
      const int src = ((seg & 7) ^ (row & 7)) << 3;
      gload16(&As[buf][(size_t)(r * 512 + wave * 64) * 8],
              &Az[(size_t)(row0 + row) * Kfull + k0 + src]);
    }
#pragma unroll
    for (int r = 0; r < 4; ++r) {                    // B: 256 rows x 8 chunks
      const int seg = r * 512 + tid;
      const int row = seg >> 3;
      const int src = ((seg & 7) ^ (row & 7)) << 3;
      gload16(&Bs[buf][(size_t)(r * 512 + wave * 64) * 8],
              &Bz[(size_t)(col0 + row) * Kfull + k0 + src]);
    }
  };

  STAGE(0, 0);
  STAGE(1, 1 < nk ? 1 : 0);
  asm volatile("s_waitcnt vmcnt(6)" ::: "memory");   // tile 0 landed, tile 1 in flight
  __builtin_amdgcn_s_barrier();
  asm volatile("" ::: "memory");

#pragma unroll 1
  for (int t = 0; t < nk; ++t) {
    const int cur = t % 3;
    STAGE((t + 2) % 3, (t + 2 < nk) ? (t + 2) : (nk - 1));   // tail: dummy restage

#pragma unroll
    for (int ks = 0; ks < 2; ++ks) {
      bf16x8 af[4], bfr[4];
#pragma unroll
      for (int fm = 0; fm < 4; ++fm) {
        const int row = wr * 64 + fm * 16 + l16;
        af[fm] = *(const bf16x8*)&As[cur][row * 64 + (((ks * 4 + g) ^ (row & 7)) << 3)];
      }
#pragma unroll
      for (int fn = 0; fn < 4; ++fn) {
        const int row = wc * 64 + fn * 16 + l16;
        bfr[fn] = *(const bf16x8*)&Bs[cur][row * 64 + (((ks * 4 + g) ^ (row & 7)) << 3)];
      }
      __builtin_amdgcn_s_setprio(1);
#pragma unroll
      for (int fm = 0; fm < 4; ++fm)
#pragma unroll
        for (int fn = 0; fn < 4; ++fn)
          acc[fm][fn] = __builtin_amdgcn_mfma_f32_16x16x32_bf16(af[fm], bfr[fn], acc[fm][fn], 0, 0, 0);
      __builtin_amdgcn_s_setprio(0);
    }

    asm volatile("s_waitcnt lgkmcnt(0)" ::: "memory");  // my reads of buf[cur] done
    asm volatile("s_waitcnt vmcnt(6)" ::: "memory");    // tile t+1 landed; t+2 in flight
    __builtin_amdgcn_s_barrier();                       // all waves done with buf[cur]
    asm volatile("" ::: "memory");
  }

  // epilogue
#pragma unroll
  for (int fn = 0; fn < 4; ++fn) {
    const int col = col0 + wc * 64 + fn * 16 + l16;
    float bv = 0.f;
    if (!SPLIT || z == 0) bv = bias[col];
#pragma unroll
    for (int fm = 0; fm < 4; ++fm) {
      const int rbase = row0 + wr * 64 + fm * 16 + g * 4;
#pragma unroll
      for (int j = 0; j < 4; ++j) {
        float v = acc[fm][fn][j] + bv;
        if (RESID) { if (!SPLIT || z == 0) v += resid[(size_t)(rbase + j) * N + col]; }
        if (RELU) v = fmaxf(v, 0.f);
        if (SPLIT) {
          float* C = z ? (float*)C1v : (float*)C0v;
          C[(size_t)(rbase + j) * N + col] = v;
        } else if (OUTBF16) {
          ((__bf16*)C0v)[(size_t)(rbase + j) * N + col] = (__bf16)v;
        } else {
          ((float*)C0v)[(size_t)(rbase + j) * N + col] = v;
        }
      }
    }
  }
}

// ---------------- flash attention (causal), swapped-QK^T, no-max softmax, paired tiles ----
// grid (32 bh, 16 pairs); block (bh,p) does q-tiles p and 31-p => uniform 33 kv-tiles.
__global__ __launch_bounds__(256)
void attn_fwd(const __bf16* __restrict__ qkv, const __bf16* __restrict__ vtg,
              __bf16* __restrict__ ctx)
{
  constexpr int S = 2048, H = 1024, W3 = 3 * H;
  __shared__ __bf16 Ks[2][64 * 64];
  __shared__ __bf16 Vt[2][64 * 64];
  __shared__ __bf16 Ps[4][16 * 64];
  const int tid = threadIdx.x, wave = tid >> 6, lane = tid & 63;
  const int g = lane >> 4, l16 = lane & 15;
  const int perm = ((l16 & 7) << 1) | (l16 >> 3);   // 4-bit row key for 8B-granular swizzle
  const int bh = blockIdx.x;
  const int b = bh >> 4, h = bh & 15;
  const size_t base = (size_t)b * S * W3;
  const __bf16* Qg = qkv + base;
  const __bf16* Kg = qkv + base + H;
  const __bf16* Vg = vtg + (size_t)bh * 64 * S;   // [d][s]

  auto STAGE_KV = [&](int buf, int kv0) {
#pragma unroll
    for (int r = 0; r < 2; ++r) {
      const int seg = r * 256 + tid;
      const int row = seg >> 3;
      const int ko = ((seg & 7) ^ (row & 7)) * 8;
      gload16(&Ks[buf][(r * 256 + wave * 64) * 8], &Kg[(size_t)(kv0 + row) * W3 + h * 64 + ko]);
      gload16(&Vt[buf][(r * 256 + wave * 64) * 8], &Vg[(size_t)row * S + kv0 + ko]);
    }
  };

#pragma unroll 1
  for (int half = 0; half < 2; ++half) {
    const int qi = half ? (31 - blockIdx.y) : blockIdx.y;
    const int q0 = qi * 64;
    const int qrow = q0 + wave * 16 + l16;
    bf16x8 qa[2];
#pragma unroll
    for (int kk = 0; kk < 2; ++kk)
      qa[kk] = *(const bf16x8*)&Qg[(size_t)qrow * W3 + h * 64 + kk * 32 + g * 8];

    f32x4 o[4] = {};
    float lsum = 0.f;
    const int nT = qi + 1;

    STAGE_KV(0, 0);
    __syncthreads();
    int cur = 0;

    for (int t = 0; t < nT; ++t) {
      const int kv0 = t * 64;
      if (t + 1 < nT) STAGE_KV(cur ^ 1, kv0 + 64);

      // S^T = K @ Q^T : lane holds q = qrow (col l16), k-rows kv0 + n*16 + g*4 + r
      f32x4 s[4] = {};
      __builtin_amdgcn_s_setprio(1);
#pragma unroll
      for (int kk = 0; kk < 2; ++kk) {
        bf16x8 kb[4];
#pragma unroll
        for (int n = 0; n < 4; ++n) {
          const int row = n * 16 + l16;
          kb[n] = *(const bf16x8*)&Ks[cur][row * 64 + ((kk * 32 + g * 8) ^ ((row & 7) << 3))];
        }
#pragma unroll
        for (int n = 0; n < 4; ++n)
          s[n] = __builtin_amdgcn_mfma_f32_16x16x32_bf16(kb[n], qa[kk], s[n], 0, 0, 0);
      }
      __builtin_amdgcn_s_setprio(0);

      // softmax-lite: p = exp2(s*log2e/8); mask only diagonal tile; deferred denominator.
      const bool diag = (t == nT - 1);
#pragma unroll
      for (int n = 0; n < 4; ++n) {
        float lp[4];
#pragma unroll
        for (int r = 0; r < 4; ++r) {
          const int ka = kv0 + n * 16 + g * 4 + r;
          float p = exp2f(s[n][r] * 0.18033688f);
          if (diag && ka > qrow) p = 0.f;
          lp[r] = p;
          lsum += p;
        }
        bf16x4 pk;
        pk[0] = (__bf16)lp[0]; pk[1] = (__bf16)lp[1];
        pk[2] = (__bf16)lp[2]; pk[3] = (__bf16)lp[3];
        // 8B-granular swizzle: h4 = 4n+g, slot = h4 ^ perm (conflict-free b64 write)
        *(bf16x4*)&Ps[wave][l16 * 64 + (((4 * n + g) ^ perm) << 2)] = pk;
      }

      // PV: O[q][d] += P[q][k] V[k][d]
      __builtin_amdgcn_s_setprio(1);
#pragma unroll
      for (int kk = 0; kk < 2; ++kk) {
        const int hb = 8 * kk + 2 * g;
        bf16x4 p0 = *(const bf16x4*)&Ps[wave][l16 * 64 + ((hb ^ perm) << 2)];
        bf16x4 p1 = *(const bf16x4*)&Ps[wave][l16 * 64 + (((hb + 1) ^ perm) << 2)];
        bf16x8 pa = __builtin_shufflevector(p0, p1, 0, 1, 2, 3, 4, 5, 6, 7);
        bf16x8 vb[4];
#pragma unroll
        for (int n2 = 0; n2 < 4; ++n2) {
          const int row = n2 * 16 + l16;
          vb[n2] = *(const bf16x8*)&Vt[cur][row * 64 + ((kk * 32 + g * 8) ^ ((row & 7) << 3))];
        }
#pragma unroll
        for (int n2 = 0; n2 < 4; ++n2)
          o[n2] = __builtin_amdgcn_mfma_f32_16x16x32_bf16(pa, vb[n2], o[n2], 0, 0, 0);
      }
      __builtin_amdgcn_s_setprio(0);
      __syncthreads();
      cur ^= 1;
    }

    // denominator: reduce per-lane partials across g-groups; broadcast to o-layout.
    lsum += __shfl_xor(lsum, 16);
    lsum += __shfl_xor(lsum, 32);
#pragma unroll
    for (int r = 0; r < 4; ++r) {
      const float den = __shfl(lsum, g * 4 + r);
      const float inv = 1.f / den;
      const int qr = q0 + wave * 16 + g * 4 + r;
#pragma unroll
      for (int n2 = 0; n2 < 4; ++n2) {
        const int d = n2 * 16 + l16;
        ctx[(size_t)(b * S + qr) * H + h * 64 + d] = (__bf16)(o[n2][r] * inv);
      }
    }
  }
}

// ---------------- LayerNorm over rows of 1024 (sums two fp32 partial inputs) -------------
template<bool WRITE_BF16, bool TWO_IN>
__global__ __launch_bounds__(256)
void ln_kernel(const float* __restrict__ in, const float* __restrict__ in2,
               const float* __restrict__ gw, const float* __restrict__ bw,
               float* __restrict__ outf, __bf16* __restrict__ outb)
{
  const int row = blockIdx.x, tid = threadIdx.x;
  float4 xv = ((const float4*)(in + (size_t)row * 1024))[tid];
  if (TWO_IN) {
    const float4 yv = ((const float4*)(in2 + (size_t)row * 1024))[tid];
    xv.x += yv.x; xv.y += yv.y; xv.z += yv.z; xv.w += yv.w;
  }
  float s = xv.x + xv.y + xv.z + xv.w;
  float s2 = xv.x * xv.x + xv.y * xv.y + xv.z * xv.z + xv.w * xv.w;
#pragma unroll
  for (int off = 32; off; off >>= 1) { s += __shfl_xor(s, off); s2 += __shfl_xor(s2, off); }
  __shared__ float ps[8];
  if ((tid & 63) == 0) { ps[tid >> 6] = s; ps[4 + (tid >> 6)] = s2; }
  __syncthreads();
  s = ps[0] + ps[1] + ps[2] + ps[3];
  s2 = ps[4] + ps[5] + ps[6] + ps[7];
  const float mean = s * (1.f / 1024.f);
  const float var = s2 * (1.f / 1024.f) - mean * mean;
  const float rs = rsqrtf(var + 1e-5f);
  const float4 gv = ((const float4*)gw)[tid];
  const float4 bv = ((const float4*)bw)[tid];
  float4 y;
  y.x = (xv.x - mean) * rs * gv.x + bv.x;
  y.y = (xv.y - mean) * rs * gv.y + bv.y;
  y.z = (xv.z - mean) * rs * gv.z + bv.z;
  y.w = (xv.w - mean) * rs * gv.w + bv.w;
  ((float4*)(outf + (size_t)row * 1024))[tid] = y;
  if (WRITE_BF16) {
    __bf16* ob = outb + (size_t)row * 1024 + tid * 4;
    ob[0] = (__bf16)y.x; ob[1] = (__bf16)y.y; ob[2] = (__bf16)y.z; ob[3] = (__bf16)y.w;
  }
}

extern "C" void kernel_launch(void* const* d_in, const int* in_sizes, int n_in,
                              void* d_out, int out_size, void* d_ws, size_t ws_size,
                              hipStream_t stream)
{
  (void)in_sizes; (void)n_in; (void)out_size; (void)ws_size;
  const float* x     = (const float*)d_in[0];
  const float* qkv_w = (const float*)d_in[2];
  const float* qkv_b = (const float*)d_in[3];
  const float* out_w = (const float*)d_in[4];
  const float* out_b = (const float*)d_in[5];
  const float* w1    = (const float*)d_in[6];
  const float* b1    = (const float*)d_in[7];
  const float* w2    = (const float*)d_in[8];
  const float* b2    = (const float*)d_in[9];
  const float* ln1g  = (const float*)d_in[10];
  const float* ln1b  = (const float*)d_in[11];
  const float* ln2g  = (const float*)d_in[12];
  const float* ln2b  = (const float*)d_in[13];

  char* ws = (char*)d_ws;
  __bf16* wt_qkv = (__bf16*)(ws + 0);          // [3072][1024]  (dead after QKV gemm)
  __bf16* wt_out = (__bf16*)(ws + 6291456);    // [1024][1024]  (dead after out-proj)
  __bf16* wt_w1  = (__bf16*)(ws + 8388608);    // [4096][1024]  (dead after FFN1)
  __bf16* wt_w2  = (__bf16*)(ws + 16777216);   // [1024][4096]
  __bf16* xb     = (__bf16*)(ws + 25165824);   // x bf16, then ctx
  __bf16* big    = (__bf16*)(ws + 33554432);   // qkv, then pB(out-proj), then h1
  float*  res    = (float*)(ws + 67108864);    // vtg, then pA(out-proj), then qA(FFN2)
  float*  x1f    = (float*)(ws + 83886080);    // ln1 out fp32
  __bf16* x1b    = (__bf16*)(ws + 100663296);  // ln1 out bf16 (dead after FFN1)
  __bf16* vtg    = (__bf16*)res;               // [32][64][2048] (dead after attn)
  float*  pB     = (float*)big;                // out-proj partial z=1 (16MB of big)
  float*  qB     = (float*)ws;                 // FFN2 partial z=1 (over dead wt_qkv/out/w1)

  transpose_cast<<<dim3(96, 32), 256, 0, stream>>>(qkv_w, wt_qkv, 1024, 3072);
  transpose_cast<<<dim3(32, 32), 256, 0, stream>>>(out_w, wt_out, 1024, 1024);
  transpose_cast<<<dim3(128, 32), 256, 0, stream>>>(w1, wt_w1, 1024, 4096);
  transpose_cast<<<dim3(32, 128), 256, 0, stream>>>(w2, wt_w2, 4096, 1024);
  cast_bf16<<<4096, 256, 0, stream>>>(x, xb);

  // QKV: 128x256 tiles, grid 32x12
  gemm3p<true, false, false, false><<<dim3(32, 12, 1), 512, 0, stream>>>(
      xb, wt_qkv, qkv_b, nullptr, big, nullptr, 4096, 3072, 1024, 1024);
  // V -> V^T per (b,h)
  vtrans<<<dim3(64, 2, 32), 256, 0, stream>>>(big, vtg);
  // attention -> ctx (reuses xb)
  attn_fwd<<<dim3(32, 16), 256, 0, stream>>>(big, vtg, xb);
  // out proj + residual(x), split-K=2 -> partials res, pB
  gemm3p<false, false, true, true><<<dim3(32, 4, 2), 512, 0, stream>>>(
      xb, wt_out, out_b, x, res, pB, 4096, 1024, 1024, 512);
  // LN1 (combines partials) -> x1f fp32, x1b bf16
  ln_kernel<true, true><<<4096, 256, 0, stream>>>(res, pB, ln1g, ln1b, x1f, x1b);
  // FFN1 + ReLU: grid 32x16 -> h1 bf16 (overwrites big)
  gemm3p<true, true, false, false><<<dim3(32, 16, 1), 512, 0, stream>>>(
      x1b, wt_w1, b1, nullptr, big, nullptr, 4096, 4096, 1024, 1024);
  // FFN2 + residual(x1f), split-K=2 -> partials res, qB
  gemm3p<false, false, true, true><<<dim3(32, 4, 2), 512, 0, stream>>>(
      big, wt_w2, b2, x1f, res, qB, 4096, 1024, 4096, 2048);
  // LN2 (combines partials) -> d_out
  ln_kernel<false, true><<<4096, 256, 0, stream>>>(res, qB, ln2g, ln2b, (float*)d_out, nullptr);
}

// Round 9
// 281.759 us; speedup vs baseline: 1.0151x; 1.0056x over previous
//
#include <hip/hip_runtime.h>
#include <hip/hip_bf16.h>

typedef __bf16 bf16x8 __attribute__((ext_vector_type(8)));
typedef __bf16 bf16x4 __attribute__((ext_vector_type(4)));
typedef float f32x4 __attribute__((ext_vector_type(4)));

__device__ __forceinline__ void gload16(void* lds, const void* g) {
  __builtin_amdgcn_global_load_lds((const __attribute__((address_space(1))) void*)g,
                                   (__attribute__((address_space(3))) void*)lds, 16, 0, 0);
}

// ---------------- weight cast+transpose: in [R][C] fp32 -> out [C][R] bf16 ----------------
__global__ __launch_bounds__(256)
void transpose_cast(const float* __restrict__ in, __bf16* __restrict__ out, int R, int C)
{
  __shared__ __bf16 tile[32][33];
  const int bc = blockIdx.x * 32, br = blockIdx.y * 32;
  const int lx = threadIdx.x & 31, ly = threadIdx.x >> 5;
#pragma unroll
  for (int p = 0; p < 4; ++p)
    tile[ly + p * 8][lx] = (__bf16)in[(size_t)(br + ly + p * 8) * C + bc + lx];
  __syncthreads();
#pragma unroll
  for (int p = 0; p < 4; ++p)
    out[(size_t)(bc + ly + p * 8) * R + br + lx] = tile[lx][ly + p * 8];
}

// ---------------- V transpose (bf16): qkv [B*S][3072] -> vtg [BH][64][2048] ----------------
__global__ __launch_bounds__(256)
void vtrans(const __bf16* __restrict__ qkv, __bf16* __restrict__ vtg)
{
  __shared__ __bf16 tile[32][33];
  const int sx = blockIdx.x * 32;
  const int dy = blockIdx.y * 32;
  const int z = blockIdx.z;
  const int b = z >> 4, h = z & 15;
  const int lx = threadIdx.x & 31, ly = threadIdx.x >> 5;
  const __bf16* src = qkv + (size_t)b * 2048 * 3072 + 2048 + h * 64;
#pragma unroll
  for (int p = 0; p < 4; ++p)
    tile[ly + p * 8][lx] = src[(size_t)(sx + ly + p * 8) * 3072 + dy + lx];
  __syncthreads();
  __bf16* dst = vtg + (size_t)z * 64 * 2048;
#pragma unroll
  for (int p = 0; p < 4; ++p)
    dst[(size_t)(dy + ly + p * 8) * 2048 + sx + lx] = tile[lx][ly + p * 8];
}

// ---------------- elementwise cast fp32 -> bf16 ----------------
__global__ __launch_bounds__(256)
void cast_bf16(const float* __restrict__ in, __bf16* __restrict__ out)
{
  const int i = (blockIdx.x * 256 + threadIdx.x) * 4;
  float4 v = *(const float4*)(in + i);
  out[i] = (__bf16)v.x; out[i + 1] = (__bf16)v.y;
  out[i + 2] = (__bf16)v.z; out[i + 3] = (__bf16)v.w;
}

// ================= 256x256 8-phase GEMM (m201-template port), BK=64, 8 waves ==============
// Waves 2M x 4N; per-wave out 128x64 (8 m-frags x 4 n-frags), acc = 128 VGPR.
// LDS: A/B tiles of 256x64 stored as 2 halves of 128x64, double-buffered = 128 KiB.
// Per K-tile t (buf p=t&1), 4 phases; phase q: {ds_read frags, stage ONE half-tile,
// barrier, lgkmcnt(0)+sched_barrier, 16 MFMA (quadrant q x K=64), barrier}.
// Stage schedule: ph0 A0(t+1)->buf[p^1], ph1 A1(t+1)->buf[p^1],
//                 ph2 B0(t+2)->buf[p].B, ph3 B1(t+2)->buf[p].B  [B(t) dead after ph0].
// vmcnt ledger: entry in-flight = B(t+1)[4]; +8 issued during t; end-of-t vmcnt(4)
// forces A(t+1),B(t+1) landed, leaves B(t+2)[4] in flight (never drains to 0).
// Race-freedom: each stage's target was last READ >=1 barrier+lgkmcnt(0) earlier
// (A[p^1]: tile t-1 ph3-end; B[p]: this tile ph0-end), and LDS writes cannot
// precede their issue point.  Tail: clamped dummy restage keeps counts uniform.
template<bool OUTBF16, bool RELU, bool SPLIT>
__global__ __launch_bounds__(512, 2)
void gemm256(const __bf16* __restrict__ A, const __bf16* __restrict__ Bt,
             const float* __restrict__ bias,
             void* __restrict__ C0v, float* __restrict__ P1,
             float* __restrict__ P2lo, float* __restrict__ P2hi,
             float* __restrict__ P3,
             int M, int N, int Kfull, int Ksub)
{
  __shared__ __align__(16) __bf16 As[2][2][128 * 64];   // [buf][half] 64 KiB
  __shared__ __align__(16) __bf16 Bs[2][2][128 * 64];   // 64 KiB  (total 128 KiB)
  const int tid = threadIdx.x, wave = tid >> 6, lane = tid & 63;
  const int g = lane >> 4, l16 = lane & 15;
  const int wr = wave >> 2, wc = wave & 3;
  const int row0 = blockIdx.x * 256, col0 = blockIdx.y * 256;
  const int z = SPLIT ? blockIdx.z : 0;
  const __bf16* Az = A + (size_t)z * Ksub;
  const __bf16* Bz = Bt + (size_t)z * Ksub;
  const int nk = Ksub >> 6;
  f32x4 acc[8][4] = {};

  // stage one 128x64 half-tile: 2 rounds x 512 thr x 16B; pre-swizzled source
  // (phys chunk c of row r holds logical chunk c ^ (r&7))
  auto SA = [&](int buf, int half, int kt) {
    const int k0 = kt << 6;
#pragma unroll
    for (int r = 0; r < 2; ++r) {
      const int seg = r * 512 + tid, rr = seg >> 3;
      const int src = ((seg & 7) ^ (rr & 7)) << 3;
      gload16(&As[buf][half][(size_t)(r * 512 + wave * 64) * 8],
              &Az[(size_t)(row0 + half * 128 + rr) * Kfull + k0 + src]);
    }
  };
  auto SB = [&](int buf, int half, int kt) {
    const int k0 = kt << 6;
#pragma unroll
    for (int r = 0; r < 2; ++r) {
      const int seg = r * 512 + tid, rr = seg >> 3;
      const int src = ((seg & 7) ^ (rr & 7)) << 3;
      gload16(&Bs[buf][half][(size_t)(r * 512 + wave * 64) * 8],
              &Bz[(size_t)(col0 + half * 128 + rr) * Kfull + k0 + src]);
    }
  };

  // prologue: tile 0 complete + B(1); leave B(1)'s 4 loads in flight
  SA(0, 0, 0); SA(0, 1, 0); SB(0, 0, 0); SB(0, 1, 0);
  { const int t1 = (nk > 1) ? 1 : 0; SB(1, 0, t1); SB(1, 1, t1); }
  asm volatile("s_waitcnt vmcnt(4)" ::: "memory");
  __builtin_amdgcn_sched_barrier(0);
  __builtin_amdgcn_s_barrier();

#pragma unroll 1
  for (int t = 0; t < nk; ++t) {
    const int p = t & 1;
    const int tA = (t + 1 < nk) ? (t + 1) : (nk - 1);
    const int tB = (t + 2 < nk) ? (t + 2) : (nk - 1);

    bf16x8 bfr[4][2], af[2][2];

    // ===== phase 0: B-all + A-q0 reads; stage A0(t+1) =====
#pragma unroll
    for (int n = 0; n < 4; ++n) {
      const int row = wc * 64 + n * 16 + l16;
      const int hf = row >> 7, rr = row & 127;
#pragma unroll
      for (int ks = 0; ks < 2; ++ks)
        bfr[n][ks] = *(const bf16x8*)&Bs[p][hf][rr * 64 + ((((ks << 2) + g) ^ (rr & 7)) << 3)];
    }
#pragma unroll
    for (int m = 0; m < 2; ++m) {
      const int rr = m * 16 + l16;
#pragma unroll
      for (int ks = 0; ks < 2; ++ks)
        af[m][ks] = *(const bf16x8*)&As[p][wr][rr * 64 + ((((ks << 2) + g) ^ (rr & 7)) << 3)];
    }
    SA(p ^ 1, 0, tA);
    __builtin_amdgcn_s_barrier();
    asm volatile("s_waitcnt lgkmcnt(0)" ::: "memory");
    __builtin_amdgcn_sched_barrier(0);
    __builtin_amdgcn_s_setprio(1);
#pragma unroll
    for (int ks = 0; ks < 2; ++ks)
#pragma unroll
      for (int m = 0; m < 2; ++m)
#pragma unroll
        for (int n = 0; n < 4; ++n)
          acc[m][n] = __builtin_amdgcn_mfma_f32_16x16x32_bf16(af[m][ks], bfr[n][ks], acc[m][n], 0, 0, 0);
    __builtin_amdgcn_s_setprio(0);
    __builtin_amdgcn_s_barrier();

    // ===== phases 1..3: A-q reads; stage A1(t+1), B0(t+2), B1(t+2) =====
#pragma unroll
    for (int q = 1; q < 4; ++q) {
#pragma unroll
      for (int m = 0; m < 2; ++m) {
        const int rr = (2 * q + m) * 16 + l16;
#pragma unroll
        for (int ks = 0; ks < 2; ++ks)
          af[m][ks] = *(const bf16x8*)&As[p][wr][rr * 64 + ((((ks << 2) + g) ^ (rr & 7)) << 3)];
      }
      if (q == 1)      SA(p ^ 1, 1, tA);
      else if (q == 2) SB(p, 0, tB);
      else             SB(p, 1, tB);
      __builtin_amdgcn_s_barrier();
      asm volatile("s_waitcnt lgkmcnt(0)" ::: "memory");
      __builtin_amdgcn_sched_barrier(0);
      __builtin_amdgcn_s_setprio(1);
#pragma unroll
      for (int ks = 0; ks < 2; ++ks)
#pragma unroll
        for (int m = 0; m < 2; ++m)
#pragma unroll
          for (int n = 0; n < 4; ++n)
            acc[2 * q + m][n] = __builtin_amdgcn_mfma_f32_16x16x32_bf16(af[m][ks], bfr[n][ks], acc[2 * q + m][n], 0, 0, 0);
      __builtin_amdgcn_s_setprio(0);
      if (q == 3) {
        asm volatile("s_waitcnt vmcnt(4)" ::: "memory");   // A(t+1),B(t+1) landed; B(t+2) in flight
        __builtin_amdgcn_sched_barrier(0);
      }
      __builtin_amdgcn_s_barrier();
    }
  }

  // ===== epilogue =====
#pragma unroll
  for (int n = 0; n < 4; ++n) {
    const int col = col0 + wc * 64 + n * 16 + l16;
    float bv = 0.f;
    if (!SPLIT || z == 0) bv = bias[col];
#pragma unroll
    for (int m = 0; m < 8; ++m) {
      const int rbase = row0 + wr * 128 + m * 16 + g * 4;
#pragma unroll
      for (int j = 0; j < 4; ++j) {
        float v = acc[m][n][j] + bv;
        const size_t idx = (size_t)(rbase + j) * N + col;
        if (SPLIT) {
          if (z == 0)      ((float*)C0v)[idx] = v;
          else if (z == 1) P1[idx] = v;
          else if (z == 2) { float* C = (row0 < 2048) ? P2lo : P2hi; C[idx] = v; }
          else             { v += P3[idx]; P3[idx] = v; }   // in-place resid add
        } else {
          if (RELU) v = fmaxf(v, 0.f);
          if (OUTBF16) ((__bf16*)C0v)[idx] = (__bf16)v;
          else         ((float*)C0v)[idx] = v;
        }
      }
    }
  }
}

// ---------------- 2-phase dbuf GEMM (r5-proven), BN=64, used for out-proj ----------------
template<int BN, bool OUT_BF16, bool RELU, bool RESID>
__global__ __launch_bounds__(256)
void gemm_bt(const __bf16* __restrict__ A, const __bf16* __restrict__ Bt,
             const float* __restrict__ bias, const float* __restrict__ resid,
             void* __restrict__ Cv, int M, int N, int K)
{
  constexpr int NW = BN / 32;
  __shared__ __bf16 As[2][128 * 64];
  __shared__ __bf16 Bs[2][BN * 64];
  const int tid = threadIdx.x;
  const int wave = tid >> 6, lane = tid & 63;
  const int g = lane >> 4, l16 = lane & 15;
  const int row0 = blockIdx.x * 128, col0 = blockIdx.y * BN;
  const int wr = wave >> 1, wc = wave & 1;
  f32x4 acc[4][NW] = {};
  const int nk = K >> 6;

  auto STAGE = [&](int buf, int k0) {
#pragma unroll
    for (int r = 0; r < 4; ++r) {
      const int seg = r * 256 + tid;
      const int arow = seg >> 3;
      const int ko = ((seg & 7) ^ (arow & 7)) * 8;
      gload16(&As[buf][(r * 256 + wave * 64) * 8], &A[(size_t)(row0 + arow) * K + k0 + ko]);
    }
#pragma unroll
    for (int r = 0; r < BN / 32; ++r) {
      const int seg = r * 256 + tid;
      const int brow = seg >> 3;
      const int ko = ((seg & 7) ^ (brow & 7)) * 8;
      gload16(&Bs[buf][(r * 256 + wave * 64) * 8], &Bt[(size_t)(col0 + brow) * K + k0 + ko]);
    }
  };

  STAGE(0, 0);
  __syncthreads();
  int cur = 0;
  for (int t = 0; t < nk; ++t) {
    if (t + 1 < nk) STAGE(cur ^ 1, (t + 1) << 6);
#pragma unroll
    for (int kk = 0; kk < 2; ++kk) {
      bf16x8 af[4], bfr[NW];
#pragma unroll
      for (int m = 0; m < 4; ++m) {
        const int row = wr * 64 + m * 16 + l16;
        af[m] = *(const bf16x8*)&As[cur][row * 64 + ((kk * 32 + g * 8) ^ ((row & 7) << 3))];
      }
#pragma unroll
      for (int n = 0; n < NW; ++n) {
        const int row = wc * (BN / 2) + n * 16 + l16;
        bfr[n] = *(const bf16x8*)&Bs[cur][row * 64 + ((kk * 32 + g * 8) ^ ((row & 7) << 3))];
      }
#pragma unroll
      for (int m = 0; m < 4; ++m)
#pragma unroll
        for (int n = 0; n < NW; ++n)
          acc[m][n] = __builtin_amdgcn_mfma_f32_16x16x32_bf16(af[m], bfr[n], acc[m][n], 0, 0, 0);
    }
    __syncthreads();
    cur ^= 1;
  }
#pragma unroll
  for (int n = 0; n < NW; ++n) {
    const int col = col0 + wc * (BN / 2) + n * 16 + l16;
    const float bv = bias[col];
#pragma unroll
    for (int m = 0; m < 4; ++m) {
      const int rrow = row0 + wr * 64 + m * 16 + g * 4;
#pragma unroll
      for (int r = 0; r < 4; ++r) {
        float v = acc[m][n][r] + bv;
        if (RESID) v += resid[(size_t)(rrow + r) * N + col];
        if (RELU)  v = fmaxf(v, 0.f);
        if (OUT_BF16) ((__bf16*)Cv)[(size_t)(rrow + r) * N + col] = (__bf16)v;
        else          ((float*)Cv)[(size_t)(rrow + r) * N + col] = v;
      }
    }
  }
}

// ---------------- flash attention (causal), swapped-QK^T, no-max softmax, paired tiles ----
__global__ __launch_bounds__(256)
void attn_fwd(const __bf16* __restrict__ qkv, const __bf16* __restrict__ vtg,
              __bf16* __restrict__ ctx)
{
  constexpr int S = 2048, H = 1024, W3 = 3 * H;
  __shared__ __bf16 Ks[2][64 * 64];
  __shared__ __bf16 Vt[2][64 * 64];
  __shared__ __bf16 Ps[4][16 * 64];
  const int tid = threadIdx.x, wave = tid >> 6, lane = tid & 63;
  const int g = lane >> 4, l16 = lane & 15;
  const int perm = ((l16 & 7) << 1) | (l16 >> 3);
  const int bh = blockIdx.x;
  const int b = bh >> 4, h = bh & 15;
  const size_t base = (size_t)b * S * W3;
  const __bf16* Qg = qkv + base;
  const __bf16* Kg = qkv + base + H;
  const __bf16* Vg = vtg + (size_t)bh * 64 * S;

  auto STAGE_KV = [&](int buf, int kv0) {
#pragma unroll
    for (int r = 0; r < 2; ++r) {
      const int seg = r * 256 + tid;
      const int row = seg >> 3;
      const int ko = ((seg & 7) ^ (row & 7)) * 8;
      gload16(&Ks[buf][(r * 256 + wave * 64) * 8], &Kg[(size_t)(kv0 + row) * W3 + h * 64 + ko]);
      gload16(&Vt[buf][(r * 256 + wave * 64) * 8], &Vg[(size_t)row * S + kv0 + ko]);
    }
  };

#pragma unroll 1
  for (int half = 0; half < 2; ++half) {
    const int qi = half ? (31 - blockIdx.y) : blockIdx.y;
    const int q0 = qi * 64;
    const int qrow = q0 + wave * 16 + l16;
    bf16x8 qa[2];
#pragma unroll
    for (int kk = 0; kk < 2; ++kk)
      qa[kk] = *(const bf16x8*)&Qg[(size_t)qrow * W3 + h * 64 + kk * 32 + g * 8];

    f32x4 o[4] = {};
    float lsum = 0.f;
    const int nT = qi + 1;

    STAGE_KV(0, 0);
    __syncthreads();
    int cur = 0;

    for (int t = 0; t < nT; ++t) {
      const int kv0 = t * 64;
      if (t + 1 < nT) STAGE_KV(cur ^ 1, kv0 + 64);

      f32x4 s[4] = {};
      __builtin_amdgcn_s_setprio(1);
#pragma unroll
      for (int kk = 0; kk < 2; ++kk) {
        bf16x8 kb[4];
#pragma unroll
        for (int n = 0; n < 4; ++n) {
          const int row = n * 16 + l16;
          kb[n] = *(const bf16x8*)&Ks[cur][row * 64 + ((kk * 32 + g * 8) ^ ((row & 7) << 3))];
        }
#pragma unroll
        for (int n = 0; n < 4; ++n)
          s[n] = __builtin_amdgcn_mfma_f32_16x16x32_bf16(kb[n], qa[kk], s[n], 0, 0, 0);
      }
      __builtin_amdgcn_s_setprio(0);

      const bool diag = (t == nT - 1);
#pragma unroll
      for (int n = 0; n < 4; ++n) {
        float lp[4];
#pragma unroll
        for (int r = 0; r < 4; ++r) {
          const int ka = kv0 + n * 16 + g * 4 + r;
          float p = exp2f(s[n][r] * 0.18033688f);
          if (diag && ka > qrow) p = 0.f;
          lp[r] = p;
          lsum += p;
        }
        bf16x4 pk;
        pk[0] = (__bf16)lp[0]; pk[1] = (__bf16)lp[1];
        pk[2] = (__bf16)lp[2]; pk[3] = (__bf16)lp[3];
        *(bf16x4*)&Ps[wave][l16 * 64 + (((4 * n + g) ^ perm) << 2)] = pk;
      }

      __builtin_amdgcn_s_setprio(1);
#pragma unroll
      for (int kk = 0; kk < 2; ++kk) {
        const int hb = 8 * kk + 2 * g;
        bf16x4 p0 = *(const bf16x4*)&Ps[wave][l16 * 64 + ((hb ^ perm) << 2)];
        bf16x4 p1 = *(const bf16x4*)&Ps[wave][l16 * 64 + (((hb + 1) ^ perm) << 2)];
        bf16x8 pa = __builtin_shufflevector(p0, p1, 0, 1, 2, 3, 4, 5, 6, 7);
        bf16x8 vb[4];
#pragma unroll
        for (int n2 = 0; n2 < 4; ++n2) {
          const int row = n2 * 16 + l16;
          vb[n2] = *(const bf16x8*)&Vt[cur][row * 64 + ((kk * 32 + g * 8) ^ ((row & 7) << 3))];
        }
#pragma unroll
        for (int n2 = 0; n2 < 4; ++n2)
          o[n2] = __builtin_amdgcn_mfma_f32_16x16x32_bf16(pa, vb[n2], o[n2], 0, 0, 0);
      }
      __builtin_amdgcn_s_setprio(0);
      __syncthreads();
      cur ^= 1;
    }

    lsum += __shfl_xor(lsum, 16);
    lsum += __shfl_xor(lsum, 32);
#pragma unroll
    for (int r = 0; r < 4; ++r) {
      const float den = __shfl(lsum, g * 4 + r);
      const float inv = 1.f / den;
      const int qr = q0 + wave * 16 + g * 4 + r;
#pragma unroll
      for (int n2 = 0; n2 < 4; ++n2) {
        const int d = n2 * 16 + l16;
        ctx[(size_t)(b * S + qr) * H + h * 64 + d] = (__bf16)(o[n2][r] * inv);
      }
    }
  }
}

// ---------------- LayerNorm over rows of 1024 (1 or 2 fp32 inputs) -----------------------
template<bool WRITE_BF16, bool TWO_IN>
__global__ __launch_bounds__(256)
void ln_kernel(const float* __restrict__ in, const float* __restrict__ in2,
               const float* __restrict__ gw, const float* __restrict__ bw,
               float* __restrict__ outf, __bf16* __restrict__ outb)
{
  const int row = blockIdx.x, tid = threadIdx.x;
  float4 xv = ((const float4*)(in + (size_t)row * 1024))[tid];
  if (TWO_IN) {
    const float4 yv = ((const float4*)(in2 + (size_t)row * 1024))[tid];
    xv.x += yv.x; xv.y += yv.y; xv.z += yv.z; xv.w += yv.w;
  }
  float s = xv.x + xv.y + xv.z + xv.w;
  float s2 = xv.x * xv.x + xv.y * xv.y + xv.z * xv.z + xv.w * xv.w;
#pragma unroll
  for (int off = 32; off; off >>= 1) { s += __shfl_xor(s, off); s2 += __shfl_xor(s2, off); }
  __shared__ float ps[8];
  if ((tid & 63) == 0) { ps[tid >> 6] = s; ps[4 + (tid >> 6)] = s2; }
  __syncthreads();
  s = ps[0] + ps[1] + ps[2] + ps[3];
  s2 = ps[4] + ps[5] + ps[6] + ps[7];
  const float mean = s * (1.f / 1024.f);
  const float var = s2 * (1.f / 1024.f) - mean * mean;
  const float rs = rsqrtf(var + 1e-5f);
  const float4 gv = ((const float4*)gw)[tid];
  const float4 bv = ((const float4*)bw)[tid];
  float4 y;
  y.x = (xv.x - mean) * rs * gv.x + bv.x;
  y.y = (xv.y - mean) * rs * gv.y + bv.y;
  y.z = (xv.z - mean) * rs * gv.z + bv.z;
  y.w = (xv.w - mean) * rs * gv.w + bv.w;
  ((float4*)(outf + (size_t)row * 1024))[tid] = y;
  if (WRITE_BF16) {
    __bf16* ob = outb + (size_t)row * 1024 + tid * 4;
    ob[0] = (__bf16)y.x; ob[1] = (__bf16)y.y; ob[2] = (__bf16)y.z; ob[3] = (__bf16)y.w;
  }
}

// ---------------- LayerNorm summing 4 split-K partials (row-split 3rd input) -------------
__global__ __launch_bounds__(256)
void ln4_kernel(const float* __restrict__ in0, const float* __restrict__ in1,
                const float* __restrict__ p2lo, const float* __restrict__ p2hi,
                const float* __restrict__ in3,
                const float* __restrict__ gw, const float* __restrict__ bw,
                float* __restrict__ outf)
{
  const int row = blockIdx.x, tid = threadIdx.x;
  const float* i2 = (row < 2048) ? p2lo : p2hi;
  float4 a = ((const float4*)(in0 + (size_t)row * 1024))[tid];
  float4 b = ((const float4*)(in1 + (size_t)row * 1024))[tid];
  float4 c = ((const float4*)(i2  + (size_t)row * 1024))[tid];
  float4 d = ((const float4*)(in3 + (size_t)row * 1024))[tid];
  float4 xv;
  xv.x = a.x + b.x + c.x + d.x; xv.y = a.y + b.y + c.y + d.y;
  xv.z = a.z + b.z + c.z + d.z; xv.w = a.w + b.w + c.w + d.w;
  float s = xv.x + xv.y + xv.z + xv.w;
  float s2 = xv.x * xv.x + xv.y * xv.y + xv.z * xv.z + xv.w * xv.w;
#pragma unroll
  for (int off = 32; off; off >>= 1) { s += __shfl_xor(s, off); s2 += __shfl_xor(s2, off); }
  __shared__ float ps[8];
  if ((tid & 63) == 0) { ps[tid >> 6] = s; ps[4 + (tid >> 6)] = s2; }
  __syncthreads();
  s = ps[0] + ps[1] + ps[2] + ps[3];
  s2 = ps[4] + ps[5] + ps[6] + ps[7];
  const float mean = s * (1.f / 1024.f);
  const float var = s2 * (1.f / 1024.f) - mean * mean;
  const float rs = rsqrtf(var + 1e-5f);
  const float4 gv = ((const float4*)gw)[tid];
  const float4 bv = ((const float4*)bw)[tid];
  float4 y;
  y.x = (xv.x - mean) * rs * gv.x + bv.x;
  y.y = (xv.y - mean) * rs * gv.y + bv.y;
  y.z = (xv.z - mean) * rs * gv.z + bv.z;
  y.w = (xv.w - mean) * rs * gv.w + bv.w;
  ((float4*)(outf + (size_t)row * 1024))[tid] = y;
}

extern "C" void kernel_launch(void* const* d_in, const int* in_sizes, int n_in,
                              void* d_out, int out_size, void* d_ws, size_t ws_size,
                              hipStream_t stream)
{
  (void)in_sizes; (void)n_in; (void)out_size; (void)ws_size;
  const float* x     = (const float*)d_in[0];
  const float* qkv_w = (const float*)d_in[2];
  const float* qkv_b = (const float*)d_in[3];
  const float* out_w = (const float*)d_in[4];
  const float* out_b = (const float*)d_in[5];
  const float* w1    = (const float*)d_in[6];
  const float* b1    = (const float*)d_in[7];
  const float* w2    = (const float*)d_in[8];
  const float* b2    = (const float*)d_in[9];
  const float* ln1g  = (const float*)d_in[10];
  const float* ln1b  = (const float*)d_in[11];
  const float* ln2g  = (const float*)d_in[12];
  const float* ln2b  = (const float*)d_in[13];

  char* ws = (char*)d_ws;
  __bf16* wt_qkv = (__bf16*)(ws + 0);          // [3072][1024]  dead after QKV
  __bf16* wt_out = (__bf16*)(ws + 6291456);    // [1024][1024]  dead after out-proj
  __bf16* wt_w1  = (__bf16*)(ws + 8388608);    // [4096][1024]  dead after FFN1
  __bf16* wt_w2  = (__bf16*)(ws + 16777216);   // [1024][4096]  live through FFN2
  __bf16* xb     = (__bf16*)(ws + 25165824);   // x bf16, then ctx; dead after out-proj
  __bf16* big    = (__bf16*)(ws + 33554432);   // qkv, then h1 (live: FFN2 A)
  float*  res    = (float*)(ws + 67108864);    // vtg, then res1; dead after LN1 -> P0
  float*  x1f    = (float*)(ws + 83886080);    // ln1 fp32; FFN2 z3 resid+partial (P3)
  __bf16* x1b    = (__bf16*)(ws + 100663296);  // ln1 bf16; dead after FFN1 -> P2hi
  __bf16* vtg    = (__bf16*)res;               // [32][64][2048] dead after attn
  float*  P1     = (float*)ws;                 // 16MB over dead wt_qkv/wt_out/wt_w1
  float*  P2lo   = (float*)xb;                 // rows 0..2047 (8MB)
  float*  P2hi   = (float*)x1b - (size_t)2048 * 1024;  // rows 2048..4095 land in x1b region

  transpose_cast<<<dim3(96, 32), 256, 0, stream>>>(qkv_w, wt_qkv, 1024, 3072);
  transpose_cast<<<dim3(32, 32), 256, 0, stream>>>(out_w, wt_out, 1024, 1024);
  transpose_cast<<<dim3(128, 32), 256, 0, stream>>>(w1, wt_w1, 1024, 4096);
  transpose_cast<<<dim3(32, 128), 256, 0, stream>>>(w2, wt_w2, 4096, 1024);
  cast_bf16<<<4096, 256, 0, stream>>>(x, xb);

  // QKV: 256x256 8-phase, grid 16x12
  gemm256<true, false, false><<<dim3(16, 12), 512, 0, stream>>>(
      xb, wt_qkv, qkv_b, big, nullptr, nullptr, nullptr, nullptr, 4096, 3072, 1024, 1024);
  // V -> V^T per (b,h)
  vtrans<<<dim3(64, 2, 32), 256, 0, stream>>>(big, vtg);
  // attention -> ctx (reuses xb)
  attn_fwd<<<dim3(32, 16), 256, 0, stream>>>(big, vtg, xb);
  // out-proj + residual(x) -> res fp32 (2-phase, proven)
  gemm_bt<64, false, false, true><<<dim3(32, 16), 256, 0, stream>>>(
      xb, wt_out, out_b, x, res, 4096, 1024, 1024);
  // LN1 -> x1f fp32, x1b bf16
  ln_kernel<true, false><<<4096, 256, 0, stream>>>(res, nullptr, ln1g, ln1b, x1f, x1b);
  // FFN1 + ReLU: 256x256 8-phase, grid 16x16 -> h1 bf16
  gemm256<true, true, false><<<dim3(16, 16), 512, 0, stream>>>(
      x1b, wt_w1, b1, big, nullptr, nullptr, nullptr, nullptr, 4096, 4096, 1024, 1024);
  // FFN2: 256x256 8-phase split-K=4, grid 16x4x4 -> partials res,P1,(P2lo/P2hi),x1f(+resid)
  gemm256<false, false, true><<<dim3(16, 4, 4), 512, 0, stream>>>(
      big, wt_w2, b2, res, P1, P2lo, P2hi, x1f, 4096, 1024, 4096, 1024);
  // LN2 sums the 4 partials -> d_out
  ln4_kernel<<<4096, 256, 0, stream>>>(res, P1, P2lo, P2hi, x1f, ln2g, ln2b,
                                       (float*)d_out);
}

// Round 10
// 250.374 us; speedup vs baseline: 1.1424x; 1.1253x over previous
//
#include <hip/hip_runtime.h>
#include <hip/hip_bf16.h>

typedef __bf16 bf16x8 __attribute__((ext_vector_type(8)));
typedef __bf16 bf16x4 __attribute__((ext_vector_type(4)));
typedef float f32x4 __attribute__((ext_vector_type(4)));

__device__ __forceinline__ void gload16(void* lds, const void* g) {
  __builtin_amdgcn_global_load_lds((const __attribute__((address_space(1))) void*)g,
                                   (__attribute__((address_space(3))) void*)lds, 16, 0, 0);
}

// ---------------- weight cast+transpose: in [R][C] fp32 -> out [C][R] bf16 ----------------
__global__ __launch_bounds__(256)
void transpose_cast(const float* __restrict__ in, __bf16* __restrict__ out, int R, int C)
{
  __shared__ __bf16 tile[32][33];
  const int bc = blockIdx.x * 32, br = blockIdx.y * 32;
  const int lx = threadIdx.x & 31, ly = threadIdx.x >> 5;
#pragma unroll
  for (int p = 0; p < 4; ++p)
    tile[ly + p * 8][lx] = (__bf16)in[(size_t)(br + ly + p * 8) * C + bc + lx];
  __syncthreads();
#pragma unroll
  for (int p = 0; p < 4; ++p)
    out[(size_t)(bc + ly + p * 8) * R + br + lx] = tile[lx][ly + p * 8];
}

// ---------------- V transpose (bf16): qkv [B*S][3072] -> vtg [BH][64][2048] ----------------
__global__ __launch_bounds__(256)
void vtrans(const __bf16* __restrict__ qkv, __bf16* __restrict__ vtg)
{
  __shared__ __bf16 tile[32][33];
  const int sx = blockIdx.x * 32;
  const int dy = blockIdx.y * 32;
  const int z = blockIdx.z;
  const int b = z >> 4, h = z & 15;
  const int lx = threadIdx.x & 31, ly = threadIdx.x >> 5;
  const __bf16* src = qkv + (size_t)b * 2048 * 3072 + 2048 + h * 64;
#pragma unroll
  for (int p = 0; p < 4; ++p)
    tile[ly + p * 8][lx] = src[(size_t)(sx + ly + p * 8) * 3072 + dy + lx];
  __syncthreads();
  __bf16* dst = vtg + (size_t)z * 64 * 2048;
#pragma unroll
  for (int p = 0; p < 4; ++p)
    dst[(size_t)(dy + ly + p * 8) * 2048 + sx + lx] = tile[lx][ly + p * 8];
}

// ---------------- elementwise cast fp32 -> bf16 ----------------
__global__ __launch_bounds__(256)
void cast_bf16(const float* __restrict__ in, __bf16* __restrict__ out)
{
  const int i = (blockIdx.x * 256 + threadIdx.x) * 4;
  float4 v = *(const float4*)(in + i);
  out[i] = (__bf16)v.x; out[i + 1] = (__bf16)v.y;
  out[i + 2] = (__bf16)v.z; out[i + 3] = (__bf16)v.w;
}

// ========= 2-phase dbuf MFMA GEMM (r5-proven structure), parametric BN/BK ================
// BK=32: LDS = 2*(128+BN)*32*2B -> 32 KB @ BN=128 (5 blocks/CU), 24 KB @ BN=64 (6/CU).
// Swizzle: physical 16B-chunk c of row r holds logical chunk c ^ KEY(r);
//   KEY = r&7 (BK=64, 8 chunks) / (r>>1)&3 (BK=32, 4 chunks) — both give 2 lanes/bank
//   on b128 frag reads (free); staged via pre-swizzled global source (gload_lds linear).
// SPLIT: blockIdx.z selects K-half; z=0 adds bias+resid; fp32 partials to C0/C1.
template<int BN, int BK, bool OUT_BF16, bool RELU, bool RESID, bool SPLIT>
__global__ __launch_bounds__(256)
void gemm_bt(const __bf16* __restrict__ A, const __bf16* __restrict__ Bt,
             const float* __restrict__ bias, const float* __restrict__ resid,
             void* __restrict__ C0v, float* __restrict__ C1,
             int M, int N, int Kfull, int Ksub)
{
  constexpr int NW = BN / 32;          // n-frags per wave
  constexpr int CH = BK / 8;           // 16B chunks per row
  __shared__ __bf16 As[2][128 * BK];
  __shared__ __bf16 Bs[2][BN * BK];
  const int tid = threadIdx.x;
  const int wave = tid >> 6, lane = tid & 63;
  const int g = lane >> 4, l16 = lane & 15;
  const int row0 = blockIdx.x * 128, col0 = blockIdx.y * BN;
  const int z = SPLIT ? blockIdx.z : 0;
  const __bf16* Az = A + (size_t)z * Ksub;
  const __bf16* Bz = Bt + (size_t)z * Ksub;
  const int wr = wave >> 1, wc = wave & 1;
  f32x4 acc[4][NW] = {};
  const int nk = Ksub / BK;

  auto KEY = [](int row) -> int { return (BK == 64) ? (row & 7) : ((row >> 1) & 3); };

  auto STAGE = [&](int buf, int k0) {
#pragma unroll
    for (int r = 0; r < 128 * CH / 256; ++r) {
      const int seg = r * 256 + tid;
      const int row = seg / CH, cp = seg % CH;
      const int src = (cp ^ KEY(row)) * 8;
      gload16(&As[buf][(r * 256 + wave * 64) * 8], &Az[(size_t)(row0 + row) * Kfull + k0 + src]);
    }
#pragma unroll
    for (int r = 0; r < BN * CH / 256; ++r) {
      const int seg = r * 256 + tid;
      const int row = seg / CH, cp = seg % CH;
      const int src = (cp ^ KEY(row)) * 8;
      gload16(&Bs[buf][(r * 256 + wave * 64) * 8], &Bz[(size_t)(col0 + row) * Kfull + k0 + src]);
    }
  };

  STAGE(0, 0);
  __syncthreads();
  int cur = 0;
  for (int t = 0; t < nk; ++t) {
    if (t + 1 < nk) STAGE(cur ^ 1, (t + 1) * BK);
#pragma unroll
    for (int kk = 0; kk < BK / 32; ++kk) {
      bf16x8 af[4], bfr[NW];
#pragma unroll
      for (int m = 0; m < 4; ++m) {
        const int row = wr * 64 + m * 16 + l16;
        af[m] = *(const bf16x8*)&As[cur][row * BK + (((kk * 4 + g) ^ KEY(row)) << 3)];
      }
#pragma unroll
      for (int n = 0; n < NW; ++n) {
        const int row = wc * (BN / 2) + n * 16 + l16;
        bfr[n] = *(const bf16x8*)&Bs[cur][row * BK + (((kk * 4 + g) ^ KEY(row)) << 3)];
      }
#pragma unroll
      for (int m = 0; m < 4; ++m)
#pragma unroll
        for (int n = 0; n < NW; ++n)
          acc[m][n] = __builtin_amdgcn_mfma_f32_16x16x32_bf16(af[m], bfr[n], acc[m][n], 0, 0, 0);
    }
    __syncthreads();
    cur ^= 1;
  }
#pragma unroll
  for (int n = 0; n < NW; ++n) {
    const int col = col0 + wc * (BN / 2) + n * 16 + l16;
    float bv = 0.f;
    if (!SPLIT || z == 0) bv = bias[col];
#pragma unroll
    for (int m = 0; m < 4; ++m) {
      const int rrow = row0 + wr * 64 + m * 16 + g * 4;
#pragma unroll
      for (int r = 0; r < 4; ++r) {
        float v = acc[m][n][r] + bv;
        const size_t idx = (size_t)(rrow + r) * N + col;
        if (SPLIT) {
          if (RESID) { if (z == 0) v += resid[idx]; }
          float* C = z ? C1 : (float*)C0v;
          C[idx] = v;
        } else {
          if (RESID) v += resid[idx];
          if (RELU)  v = fmaxf(v, 0.f);
          if (OUT_BF16) ((__bf16*)C0v)[idx] = (__bf16)v;
          else          ((float*)C0v)[idx] = v;
        }
      }
    }
  }
}

// ---------------- flash attention (causal), swapped-QK^T, no-max softmax, paired tiles ----
// grid (32 bh, 16 pairs); block (bh,p) does q-tiles p and 31-p => uniform 33 kv-tiles.
__global__ __launch_bounds__(256)
void attn_fwd(const __bf16* __restrict__ qkv, const __bf16* __restrict__ vtg,
              __bf16* __restrict__ ctx)
{
  constexpr int S = 2048, H = 1024, W3 = 3 * H;
  __shared__ __bf16 Ks[2][64 * 64];
  __shared__ __bf16 Vt[2][64 * 64];
  __shared__ __bf16 Ps[4][16 * 64];
  const int tid = threadIdx.x, wave = tid >> 6, lane = tid & 63;
  const int g = lane >> 4, l16 = lane & 15;
  const int perm = ((l16 & 7) << 1) | (l16 >> 3);
  const int bh = blockIdx.x;
  const int b = bh >> 4, h = bh & 15;
  const size_t base = (size_t)b * S * W3;
  const __bf16* Qg = qkv + base;
  const __bf16* Kg = qkv + base + H;
  const __bf16* Vg = vtg + (size_t)bh * 64 * S;

  auto STAGE_KV = [&](int buf, int kv0) {
#pragma unroll
    for (int r = 0; r < 2; ++r) {
      const int seg = r * 256 + tid;
      const int row = seg >> 3;
      const int ko = ((seg & 7) ^ (row & 7)) * 8;
      gload16(&Ks[buf][(r * 256 + wave * 64) * 8], &Kg[(size_t)(kv0 + row) * W3 + h * 64 + ko]);
      gload16(&Vt[buf][(r * 256 + wave * 64) * 8], &Vg[(size_t)row * S + kv0 + ko]);
    }
  };

#pragma unroll 1
  for (int half = 0; half < 2; ++half) {
    const int qi = half ? (31 - blockIdx.y) : blockIdx.y;
    const int q0 = qi * 64;
    const int qrow = q0 + wave * 16 + l16;
    bf16x8 qa[2];
#pragma unroll
    for (int kk = 0; kk < 2; ++kk)
      qa[kk] = *(const bf16x8*)&Qg[(size_t)qrow * W3 + h * 64 + kk * 32 + g * 8];

    f32x4 o[4] = {};
    float lsum = 0.f;
    const int nT = qi + 1;

    STAGE_KV(0, 0);
    __syncthreads();
    int cur = 0;

    for (int t = 0; t < nT; ++t) {
      const int kv0 = t * 64;
      if (t + 1 < nT) STAGE_KV(cur ^ 1, kv0 + 64);

      f32x4 s[4] = {};
      __builtin_amdgcn_s_setprio(1);
#pragma unroll
      for (int kk = 0; kk < 2; ++kk) {
        bf16x8 kb[4];
#pragma unroll
        for (int n = 0; n < 4; ++n) {
          const int row = n * 16 + l16;
          kb[n] = *(const bf16x8*)&Ks[cur][row * 64 + ((kk * 32 + g * 8) ^ ((row & 7) << 3))];
        }
#pragma unroll
        for (int n = 0; n < 4; ++n)
          s[n] = __builtin_amdgcn_mfma_f32_16x16x32_bf16(kb[n], qa[kk], s[n], 0, 0, 0);
      }
      __builtin_amdgcn_s_setprio(0);

      const bool diag = (t == nT - 1);
#pragma unroll
      for (int n = 0; n < 4; ++n) {
        float lp[4];
#pragma unroll
        for (int r = 0; r < 4; ++r) {
          const int ka = kv0 + n * 16 + g * 4 + r;
          float p = exp2f(s[n][r] * 0.18033688f);
          if (diag && ka > qrow) p = 0.f;
          lp[r] = p;
          lsum += p;
        }
        bf16x4 pk;
        pk[0] = (__bf16)lp[0]; pk[1] = (__bf16)lp[1];
        pk[2] = (__bf16)lp[2]; pk[3] = (__bf16)lp[3];
        *(bf16x4*)&Ps[wave][l16 * 64 + (((4 * n + g) ^ perm) << 2)] = pk;
      }

      __builtin_amdgcn_s_setprio(1);
#pragma unroll
      for (int kk = 0; kk < 2; ++kk) {
        const int hb = 8 * kk + 2 * g;
        bf16x4 p0 = *(const bf16x4*)&Ps[wave][l16 * 64 + ((hb ^ perm) << 2)];
        bf16x4 p1 = *(const bf16x4*)&Ps[wave][l16 * 64 + (((hb + 1) ^ perm) << 2)];
        bf16x8 pa = __builtin_shufflevector(p0, p1, 0, 1, 2, 3, 4, 5, 6, 7);
        bf16x8 vb[4];
#pragma unroll
        for (int n2 = 0; n2 < 4; ++n2) {
          const int row = n2 * 16 + l16;
          vb[n2] = *(const bf16x8*)&Vt[cur][row * 64 + ((kk * 32 + g * 8) ^ ((row & 7) << 3))];
        }
#pragma unroll
        for (int n2 = 0; n2 < 4; ++n2)
          o[n2] = __builtin_amdgcn_mfma_f32_16x16x32_bf16(pa, vb[n2], o[n2], 0, 0, 0);
      }
      __builtin_amdgcn_s_setprio(0);
      __syncthreads();
      cur ^= 1;
    }

    lsum += __shfl_xor(lsum, 16);
    lsum += __shfl_xor(lsum, 32);
#pragma unroll
    for (int r = 0; r < 4; ++r) {
      const float den = __shfl(lsum, g * 4 + r);
      const float inv = 1.f / den;
      const int qr = q0 + wave * 16 + g * 4 + r;
#pragma unroll
      for (int n2 = 0; n2 < 4; ++n2) {
        const int d = n2 * 16 + l16;
        ctx[(size_t)(b * S + qr) * H + h * 64 + d] = (__bf16)(o[n2][r] * inv);
      }
    }
  }
}

// ---------------- LayerNorm over rows of 1024 (1 or 2 fp32 inputs) -----------------------
template<bool WRITE_BF16, bool TWO_IN>
__global__ __launch_bounds__(256)
void ln_kernel(const float* __restrict__ in, const float* __restrict__ in2,
               const float* __restrict__ gw, const float* __restrict__ bw,
               float* __restrict__ outf, __bf16* __restrict__ outb)
{
  const int row = blockIdx.x, tid = threadIdx.x;
  float4 xv = ((const float4*)(in + (size_t)row * 1024))[tid];
  if (TWO_IN) {
    const float4 yv = ((const float4*)(in2 + (size_t)row * 1024))[tid];
    xv.x += yv.x; xv.y += yv.y; xv.z += yv.z; xv.w += yv.w;
  }
  float s = xv.x + xv.y + xv.z + xv.w;
  float s2 = xv.x * xv.x + xv.y * xv.y + xv.z * xv.z + xv.w * xv.w;
#pragma unroll
  for (int off = 32; off; off >>= 1) { s += __shfl_xor(s, off); s2 += __shfl_xor(s2, off); }
  __shared__ float ps[8];
  if ((tid & 63) == 0) { ps[tid >> 6] = s; ps[4 + (tid >> 6)] = s2; }
  __syncthreads();
  s = ps[0] + ps[1] + ps[2] + ps[3];
  s2 = ps[4] + ps[5] + ps[6] + ps[7];
  const float mean = s * (1.f / 1024.f);
  const float var = s2 * (1.f / 1024.f) - mean * mean;
  const float rs = rsqrtf(var + 1e-5f);
  const float4 gv = ((const float4*)gw)[tid];
  const float4 bv = ((const float4*)bw)[tid];
  float4 y;
  y.x = (xv.x - mean) * rs * gv.x + bv.x;
  y.y = (xv.y - mean) * rs * gv.y + bv.y;
  y.z = (xv.z - mean) * rs * gv.z + bv.z;
  y.w = (xv.w - mean) * rs * gv.w + bv.w;
  ((float4*)(outf + (size_t)row * 1024))[tid] = y;
  if (WRITE_BF16) {
    __bf16* ob = outb + (size_t)row * 1024 + tid * 4;
    ob[0] = (__bf16)y.x; ob[1] = (__bf16)y.y; ob[2] = (__bf16)y.z; ob[3] = (__bf16)y.w;
  }
}

extern "C" void kernel_launch(void* const* d_in, const int* in_sizes, int n_in,
                              void* d_out, int out_size, void* d_ws, size_t ws_size,
                              hipStream_t stream)
{
  (void)in_sizes; (void)n_in; (void)out_size; (void)ws_size;
  const float* x     = (const float*)d_in[0];
  const float* qkv_w = (const float*)d_in[2];
  const float* qkv_b = (const float*)d_in[3];
  const float* out_w = (const float*)d_in[4];
  const float* out_b = (const float*)d_in[5];
  const float* w1    = (const float*)d_in[6];
  const float* b1    = (const float*)d_in[7];
  const float* w2    = (const float*)d_in[8];
  const float* b2    = (const float*)d_in[9];
  const float* ln1g  = (const float*)d_in[10];
  const float* ln1b  = (const float*)d_in[11];
  const float* ln2g  = (const float*)d_in[12];
  const float* ln2b  = (const float*)d_in[13];

  char* ws = (char*)d_ws;
  __bf16* wt_qkv = (__bf16*)(ws + 0);          // [3072][1024]  dead after QKV
  __bf16* wt_out = (__bf16*)(ws + 6291456);    // [1024][1024]  dead after out-proj
  __bf16* wt_w1  = (__bf16*)(ws + 8388608);    // [4096][1024]  dead after FFN1
  __bf16* wt_w2  = (__bf16*)(ws + 16777216);   // [1024][4096]  live through FFN2
  __bf16* xb     = (__bf16*)(ws + 25165824);   // x bf16, then ctx
  __bf16* big    = (__bf16*)(ws + 33554432);   // qkv, then h1
  float*  res    = (float*)(ws + 67108864);    // vtg, then res1, then FFN2 partial z=0
  float*  x1f    = (float*)(ws + 83886080);    // ln1 out fp32
  __bf16* x1b    = (__bf16*)(ws + 100663296);  // ln1 out bf16 (dead after FFN1)
  __bf16* vtg    = (__bf16*)res;               // [32][64][2048] (dead after attn)
  float*  qB     = (float*)ws;                 // FFN2 partial z=1 (over dead wt_qkv/out/w1)

  transpose_cast<<<dim3(96, 32), 256, 0, stream>>>(qkv_w, wt_qkv, 1024, 3072);
  transpose_cast<<<dim3(32, 32), 256, 0, stream>>>(out_w, wt_out, 1024, 1024);
  transpose_cast<<<dim3(128, 32), 256, 0, stream>>>(w1, wt_w1, 1024, 4096);
  transpose_cast<<<dim3(32, 128), 256, 0, stream>>>(w2, wt_w2, 4096, 1024);
  cast_bf16<<<4096, 256, 0, stream>>>(x, xb);

  // QKV: BN=128, BK=32 (5 blocks/CU), grid 32x24
  gemm_bt<128, 32, true, false, false, false><<<dim3(32, 24), 256, 0, stream>>>(
      xb, wt_qkv, qkv_b, nullptr, big, nullptr, 4096, 3072, 1024, 1024);
  // V -> V^T per (b,h)
  vtrans<<<dim3(64, 2, 32), 256, 0, stream>>>(big, vtg);
  // attention -> ctx (reuses xb)
  attn_fwd<<<dim3(32, 16), 256, 0, stream>>>(big, vtg, xb);
  // out-proj + residual(x) -> res fp32 ; BN=64, BK=32 (6 blocks/CU), grid 32x16
  gemm_bt<64, 32, false, false, true, false><<<dim3(32, 16), 256, 0, stream>>>(
      xb, wt_out, out_b, x, res, nullptr, 4096, 1024, 1024, 1024);
  // LN1 -> x1f fp32, x1b bf16
  ln_kernel<true, false><<<4096, 256, 0, stream>>>(res, nullptr, ln1g, ln1b, x1f, x1b);
  // FFN1 + ReLU: BN=128, BK=32, grid 32x32 -> h1 bf16
  gemm_bt<128, 32, true, true, false, false><<<dim3(32, 32), 256, 0, stream>>>(
      x1b, wt_w1, b1, nullptr, big, nullptr, 4096, 4096, 1024, 1024);
  // FFN2 + residual(x1f): BN=128, BK=32, split-K=2, grid 32x8x2 -> partials res, qB
  gemm_bt<128, 32, false, false, true, true><<<dim3(32, 8, 2), 256, 0, stream>>>(
      big, wt_w2, b2, x1f, res, qB, 4096, 1024, 4096, 2048);
  // LN2 (combines partials) -> d_out
  ln_kernel<false, true><<<4096, 256, 0, stream>>>(res, qB, ln2g, ln2b, (float*)d_out, nullptr);
}

// Round 11
// 233.778 us; speedup vs baseline: 1.2235x; 1.0710x over previous
//
#include <hip/hip_runtime.h>
#include <hip/hip_bf16.h>

typedef __bf16 bf16x8 __attribute__((ext_vector_type(8)));
typedef __bf16 bf16x4 __attribute__((ext_vector_type(4)));
typedef float f32x4 __attribute__((ext_vector_type(4)));

__device__ __forceinline__ void gload16(void* lds, const void* g) {
  __builtin_amdgcn_global_load_lds((const __attribute__((address_space(1))) void*)g,
                                   (__attribute__((address_space(3))) void*)lds, 16, 0, 0);
}

// ---------------- weight cast+transpose: in [R][C] fp32 -> out [C][R] bf16 ----------------
__global__ __launch_bounds__(256)
void transpose_cast(const float* __restrict__ in, __bf16* __restrict__ out, int R, int C)
{
  __shared__ __bf16 tile[32][33];
  const int bc = blockIdx.x * 32, br = blockIdx.y * 32;
  const int lx = threadIdx.x & 31, ly = threadIdx.x >> 5;
#pragma unroll
  for (int p = 0; p < 4; ++p)
    tile[ly + p * 8][lx] = (__bf16)in[(size_t)(br + ly + p * 8) * C + bc + lx];
  __syncthreads();
#pragma unroll
  for (int p = 0; p < 4; ++p)
    out[(size_t)(bc + ly + p * 8) * R + br + lx] = tile[lx][ly + p * 8];
}

// ---------------- V transpose (bf16): qkv [B*S][3072] -> vtg [BH][64][2048] ----------------
__global__ __launch_bounds__(256)
void vtrans(const __bf16* __restrict__ qkv, __bf16* __restrict__ vtg)
{
  __shared__ __bf16 tile[32][33];
  const int sx = blockIdx.x * 32;
  const int dy = blockIdx.y * 32;
  const int z = blockIdx.z;
  const int b = z >> 4, h = z & 15;
  const int lx = threadIdx.x & 31, ly = threadIdx.x >> 5;
  const __bf16* src = qkv + (size_t)b * 2048 * 3072 + 2048 + h * 64;
#pragma unroll
  for (int p = 0; p < 4; ++p)
    tile[ly + p * 8][lx] = src[(size_t)(sx + ly + p * 8) * 3072 + dy + lx];
  __syncthreads();
  __bf16* dst = vtg + (size_t)z * 64 * 2048;
#pragma unroll
  for (int p = 0; p < 4; ++p)
    dst[(size_t)(dy + ly + p * 8) * 2048 + sx + lx] = tile[lx][ly + p * 8];
}

// ---------------- elementwise cast fp32 -> bf16 ----------------
__global__ __launch_bounds__(256)
void cast_bf16(const float* __restrict__ in, __bf16* __restrict__ out)
{
  const int i = (blockIdx.x * 256 + threadIdx.x) * 4;
  float4 v = *(const float4*)(in + i);
  out[i] = (__bf16)v.x; out[i + 1] = (__bf16)v.y;
  out[i + 2] = (__bf16)v.z; out[i + 3] = (__bf16)v.w;
}

// ========= 2-phase dbuf MFMA GEMM (proven structure), parametric BN/BK ====================
// RBF16: residual stream is bf16 (saves bandwidth; used by FFN2 with LN1's bf16 output).
// SPLIT: blockIdx.z selects K-half; z=0 adds bias+resid; fp32 partials to C0/C1.
template<int BN, int BK, bool OUT_BF16, bool RELU, bool RESID, bool RBF16, bool SPLIT>
__global__ __launch_bounds__(256)
void gemm_bt(const __bf16* __restrict__ A, const __bf16* __restrict__ Bt,
             const float* __restrict__ bias, const void* __restrict__ residv,
             void* __restrict__ C0v, float* __restrict__ C1,
             int M, int N, int Kfull, int Ksub)
{
  constexpr int NW = BN / 32;          // n-frags per wave
  constexpr int CH = BK / 8;           // 16B chunks per row
  __shared__ __bf16 As[2][128 * BK];
  __shared__ __bf16 Bs[2][BN * BK];
  const int tid = threadIdx.x;
  const int wave = tid >> 6, lane = tid & 63;
  const int g = lane >> 4, l16 = lane & 15;
  const int row0 = blockIdx.x * 128, col0 = blockIdx.y * BN;
  const int z = SPLIT ? blockIdx.z : 0;
  const __bf16* Az = A + (size_t)z * Ksub;
  const __bf16* Bz = Bt + (size_t)z * Ksub;
  const int wr = wave >> 1, wc = wave & 1;
  f32x4 acc[4][NW] = {};
  const int nk = Ksub / BK;

  auto KEY = [](int row) -> int { return (BK == 64) ? (row & 7) : ((row >> 1) & 3); };

  auto STAGE = [&](int buf, int k0) {
#pragma unroll
    for (int r = 0; r < 128 * CH / 256; ++r) {
      const int seg = r * 256 + tid;
      const int row = seg / CH, cp = seg % CH;
      const int src = (cp ^ KEY(row)) * 8;
      gload16(&As[buf][(r * 256 + wave * 64) * 8], &Az[(size_t)(row0 + row) * Kfull + k0 + src]);
    }
#pragma unroll
    for (int r = 0; r < BN * CH / 256; ++r) {
      const int seg = r * 256 + tid;
      const int row = seg / CH, cp = seg % CH;
      const int src = (cp ^ KEY(row)) * 8;
      gload16(&Bs[buf][(r * 256 + wave * 64) * 8], &Bz[(size_t)(col0 + row) * Kfull + k0 + src]);
    }
  };

  STAGE(0, 0);
  __syncthreads();
  int cur = 0;
  for (int t = 0; t < nk; ++t) {
    if (t + 1 < nk) STAGE(cur ^ 1, (t + 1) * BK);
#pragma unroll
    for (int kk = 0; kk < BK / 32; ++kk) {
      bf16x8 af[4], bfr[NW];
#pragma unroll
      for (int m = 0; m < 4; ++m) {
        const int row = wr * 64 + m * 16 + l16;
        af[m] = *(const bf16x8*)&As[cur][row * BK + (((kk * 4 + g) ^ KEY(row)) << 3)];
      }
#pragma unroll
      for (int n = 0; n < NW; ++n) {
        const int row = wc * (BN / 2) + n * 16 + l16;
        bfr[n] = *(const bf16x8*)&Bs[cur][row * BK + (((kk * 4 + g) ^ KEY(row)) << 3)];
      }
#pragma unroll
      for (int m = 0; m < 4; ++m)
#pragma unroll
        for (int n = 0; n < NW; ++n)
          acc[m][n] = __builtin_amdgcn_mfma_f32_16x16x32_bf16(af[m], bfr[n], acc[m][n], 0, 0, 0);
    }
    __syncthreads();
    cur ^= 1;
  }
#pragma unroll
  for (int n = 0; n < NW; ++n) {
    const int col = col0 + wc * (BN / 2) + n * 16 + l16;
    float bv = 0.f;
    if (!SPLIT || z == 0) bv = bias[col];
#pragma unroll
    for (int m = 0; m < 4; ++m) {
      const int rrow = row0 + wr * 64 + m * 16 + g * 4;
#pragma unroll
      for (int r = 0; r < 4; ++r) {
        float v = acc[m][n][r] + bv;
        const size_t idx = (size_t)(rrow + r) * N + col;
        if (RESID && (!SPLIT || z == 0)) {
          if (RBF16) v += (float)((const __bf16*)residv)[idx];
          else       v += ((const float*)residv)[idx];
        }
        if (SPLIT) {
          float* C = z ? C1 : (float*)C0v;
          C[idx] = v;
        } else {
          if (RELU)  v = fmaxf(v, 0.f);
          if (OUT_BF16) ((__bf16*)C0v)[idx] = (__bf16)v;
          else          ((float*)C0v)[idx] = v;
        }
      }
    }
  }
}

// ---------------- flash attention (causal), swapped-QK^T, no-max softmax, paired tiles ----
// grid (32 bh, 16 pairs); block (bh,p) does q-tiles p and 31-p => uniform 33 kv-tiles.
__global__ __launch_bounds__(256)
void attn_fwd(const __bf16* __restrict__ qkv, const __bf16* __restrict__ vtg,
              __bf16* __restrict__ ctx)
{
  constexpr int S = 2048, H = 1024, W3 = 3 * H;
  __shared__ __bf16 Ks[2][64 * 64];
  __shared__ __bf16 Vt[2][64 * 64];
  __shared__ __bf16 Ps[4][16 * 64];
  const int tid = threadIdx.x, wave = tid >> 6, lane = tid & 63;
  const int g = lane >> 4, l16 = lane & 15;
  const int perm = ((l16 & 7) << 1) | (l16 >> 3);
  const int bh = blockIdx.x;
  const int b = bh >> 4, h = bh & 15;
  const size_t base = (size_t)b * S * W3;
  const __bf16* Qg = qkv + base;
  const __bf16* Kg = qkv + base + H;
  const __bf16* Vg = vtg + (size_t)bh * 64 * S;

  auto STAGE_KV = [&](int buf, int kv0) {
#pragma unroll
    for (int r = 0; r < 2; ++r) {
      const int seg = r * 256 + tid;
      const int row = seg >> 3;
      const int ko = ((seg & 7) ^ (row & 7)) * 8;
      gload16(&Ks[buf][(r * 256 + wave * 64) * 8], &Kg[(size_t)(kv0 + row) * W3 + h * 64 + ko]);
      gload16(&Vt[buf][(r * 256 + wave * 64) * 8], &Vg[(size_t)row * S + kv0 + ko]);
    }
  };

#pragma unroll 1
  for (int half = 0; half < 2; ++half) {
    const int qi = half ? (31 - blockIdx.y) : blockIdx.y;
    const int q0 = qi * 64;
    const int qrow = q0 + wave * 16 + l16;
    bf16x8 qa[2];
#pragma unroll
    for (int kk = 0; kk < 2; ++kk)
      qa[kk] = *(const bf16x8*)&Qg[(size_t)qrow * W3 + h * 64 + kk * 32 + g * 8];

    f32x4 o[4] = {};
    float lsum = 0.f;
    const int nT = qi + 1;

    STAGE_KV(0, 0);
    __syncthreads();
    int cur = 0;

    for (int t = 0; t < nT; ++t) {
      const int kv0 = t * 64;
      if (t + 1 < nT) STAGE_KV(cur ^ 1, kv0 + 64);

      f32x4 s[4] = {};
      __builtin_amdgcn_s_setprio(1);
#pragma unroll
      for (int kk = 0; kk < 2; ++kk) {
        bf16x8 kb[4];
#pragma unroll
        for (int n = 0; n < 4; ++n) {
          const int row = n * 16 + l16;
          kb[n] = *(const bf16x8*)&Ks[cur][row * 64 + ((kk * 32 + g * 8) ^ ((row & 7) << 3))];
        }
#pragma unroll
        for (int n = 0; n < 4; ++n)
          s[n] = __builtin_amdgcn_mfma_f32_16x16x32_bf16(kb[n], qa[kk], s[n], 0, 0, 0);
      }
      __builtin_amdgcn_s_setprio(0);

      const bool diag = (t == nT - 1);
#pragma unroll
      for (int n = 0; n < 4; ++n) {
        float lp[4];
#pragma unroll
        for (int r = 0; r < 4; ++r) {
          const int ka = kv0 + n * 16 + g * 4 + r;
          float p = exp2f(s[n][r] * 0.18033688f);
          if (diag && ka > qrow) p = 0.f;
          lp[r] = p;
          lsum += p;
        }
        bf16x4 pk;
        pk[0] = (__bf16)lp[0]; pk[1] = (__bf16)lp[1];
        pk[2] = (__bf16)lp[2]; pk[3] = (__bf16)lp[3];
        *(bf16x4*)&Ps[wave][l16 * 64 + (((4 * n + g) ^ perm) << 2)] = pk;
      }

      __builtin_amdgcn_s_setprio(1);
#pragma unroll
      for (int kk = 0; kk < 2; ++kk) {
        const int hb = 8 * kk + 2 * g;
        bf16x4 p0 = *(const bf16x4*)&Ps[wave][l16 * 64 + ((hb ^ perm) << 2)];
        bf16x4 p1 = *(const bf16x4*)&Ps[wave][l16 * 64 + (((hb + 1) ^ perm) << 2)];
        bf16x8 pa = __builtin_shufflevector(p0, p1, 0, 1, 2, 3, 4, 5, 6, 7);
        bf16x8 vb[4];
#pragma unroll
        for (int n2 = 0; n2 < 4; ++n2) {
          const int row = n2 * 16 + l16;
          vb[n2] = *(const bf16x8*)&Vt[cur][row * 64 + ((kk * 32 + g * 8) ^ ((row & 7) << 3))];
        }
#pragma unroll
        for (int n2 = 0; n2 < 4; ++n2)
          o[n2] = __builtin_amdgcn_mfma_f32_16x16x32_bf16(pa, vb[n2], o[n2], 0, 0, 0);
      }
      __builtin_amdgcn_s_setprio(0);
      __syncthreads();
      cur ^= 1;
    }

    lsum += __shfl_xor(lsum, 16);
    lsum += __shfl_xor(lsum, 32);
#pragma unroll
    for (int r = 0; r < 4; ++r) {
      const float den = __shfl(lsum, g * 4 + r);
      const float inv = 1.f / den;
      const int qr = q0 + wave * 16 + g * 4 + r;
#pragma unroll
      for (int n2 = 0; n2 < 4; ++n2) {
        const int d = n2 * 16 + l16;
        ctx[(size_t)(b * S + qr) * H + h * 64 + d] = (__bf16)(o[n2][r] * inv);
      }
    }
  }
}

// ---------------- LayerNorm over rows of 1024 (1 or 2 fp32 inputs) -----------------------
template<bool WRITE_F32, bool WRITE_BF16, bool TWO_IN>
__global__ __launch_bounds__(256)
void ln_kernel(const float* __restrict__ in, const float* __restrict__ in2,
               const float* __restrict__ gw, const float* __restrict__ bw,
               float* __restrict__ outf, __bf16* __restrict__ outb)
{
  const int row = blockIdx.x, tid = threadIdx.x;
  float4 xv = ((const float4*)(in + (size_t)row * 1024))[tid];
  if (TWO_IN) {
    const float4 yv = ((const float4*)(in2 + (size_t)row * 1024))[tid];
    xv.x += yv.x; xv.y += yv.y; xv.z += yv.z; xv.w += yv.w;
  }
  float s = xv.x + xv.y + xv.z + xv.w;
  float s2 = xv.x * xv.x + xv.y * xv.y + xv.z * xv.z + xv.w * xv.w;
#pragma unroll
  for (int off = 32; off; off >>= 1) { s += __shfl_xor(s, off); s2 += __shfl_xor(s2, off); }
  __shared__ float ps[8];
  if ((tid & 63) == 0) { ps[tid >> 6] = s; ps[4 + (tid >> 6)] = s2; }
  __syncthreads();
  s = ps[0] + ps[1] + ps[2] + ps[3];
  s2 = ps[4] + ps[5] + ps[6] + ps[7];
  const float mean = s * (1.f / 1024.f);
  const float var = s2 * (1.f / 1024.f) - mean * mean;
  const float rs = rsqrtf(var + 1e-5f);
  const float4 gv = ((const float4*)gw)[tid];
  const float4 bv = ((const float4*)bw)[tid];
  float4 y;
  y.x = (xv.x - mean) * rs * gv.x + bv.x;
  y.y = (xv.y - mean) * rs * gv.y + bv.y;
  y.z = (xv.z - mean) * rs * gv.z + bv.z;
  y.w = (xv.w - mean) * rs * gv.w + bv.w;
  if (WRITE_F32)
    ((float4*)(outf + (size_t)row * 1024))[tid] = y;
  if (WRITE_BF16) {
    __bf16* ob = outb + (size_t)row * 1024 + tid * 4;
    ob[0] = (__bf16)y.x; ob[1] = (__bf16)y.y; ob[2] = (__bf16)y.z; ob[3] = (__bf16)y.w;
  }
}

extern "C" void kernel_launch(void* const* d_in, const int* in_sizes, int n_in,
                              void* d_out, int out_size, void* d_ws, size_t ws_size,
                              hipStream_t stream)
{
  (void)in_sizes; (void)n_in; (void)out_size; (void)ws_size;
  const float* x     = (const float*)d_in[0];
  const float* qkv_w = (const float*)d_in[2];
  const float* qkv_b = (const float*)d_in[3];
  const float* out_w = (const float*)d_in[4];
  const float* out_b = (const float*)d_in[5];
  const float* w1    = (const float*)d_in[6];
  const float* b1    = (const float*)d_in[7];
  const float* w2    = (const float*)d_in[8];
  const float* b2    = (const float*)d_in[9];
  const float* ln1g  = (const float*)d_in[10];
  const float* ln1b  = (const float*)d_in[11];
  const float* ln2g  = (const float*)d_in[12];
  const float* ln2b  = (const float*)d_in[13];

  char* ws = (char*)d_ws;
  __bf16* wt_qkv = (__bf16*)(ws + 0);          // [3072][1024]  dead after QKV
  __bf16* wt_out = (__bf16*)(ws + 6291456);    // [1024][1024]  dead after out-proj
  __bf16* wt_w1  = (__bf16*)(ws + 8388608);    // [4096][1024]  dead after FFN1
  __bf16* wt_w2  = (__bf16*)(ws + 16777216);   // [1024][4096]  live through FFN2
  __bf16* xb     = (__bf16*)(ws + 25165824);   // x bf16, then ctx
  __bf16* big    = (__bf16*)(ws + 33554432);   // qkv, then h1
  float*  res    = (float*)(ws + 67108864);    // vtg, then res1, then FFN2 partial z=0
  __bf16* x1b    = (__bf16*)(ws + 100663296);  // ln1 out bf16 (FFN1 A + FFN2 resid)
  __bf16* vtg    = (__bf16*)res;               // [32][64][2048] (dead after attn)
  float*  qB     = (float*)ws;                 // FFN2 partial z=1 (over dead wt buffers, 16MB)

  transpose_cast<<<dim3(96, 32), 256, 0, stream>>>(qkv_w, wt_qkv, 1024, 3072);
  transpose_cast<<<dim3(32, 32), 256, 0, stream>>>(out_w, wt_out, 1024, 1024);
  transpose_cast<<<dim3(128, 32), 256, 0, stream>>>(w1, wt_w1, 1024, 4096);
  transpose_cast<<<dim3(32, 128), 256, 0, stream>>>(w2, wt_w2, 4096, 1024);
  cast_bf16<<<4096, 256, 0, stream>>>(x, xb);

  // QKV: BN=128, BK=64, grid 32x24
  gemm_bt<128, 64, true, false, false, false, false><<<dim3(32, 24), 256, 0, stream>>>(
      xb, wt_qkv, qkv_b, nullptr, big, nullptr, 4096, 3072, 1024, 1024);
  // V -> V^T per (b,h)
  vtrans<<<dim3(64, 2, 32), 256, 0, stream>>>(big, vtg);
  // attention -> ctx (reuses xb)
  attn_fwd<<<dim3(32, 16), 256, 0, stream>>>(big, vtg, xb);
  // out-proj + residual(x fp32) -> res fp32 ; BN=64, BK=64, grid 32x16
  gemm_bt<64, 64, false, false, true, false, false><<<dim3(32, 16), 256, 0, stream>>>(
      xb, wt_out, out_b, x, res, nullptr, 4096, 1024, 1024, 1024);
  // LN1 -> x1b bf16 only
  ln_kernel<false, true, false><<<4096, 256, 0, stream>>>(res, nullptr, ln1g, ln1b,
                                                          nullptr, x1b);
  // FFN1 + ReLU: BN=128, BK=64, grid 32x32 -> h1 bf16
  gemm_bt<128, 64, true, true, false, false, false><<<dim3(32, 32), 256, 0, stream>>>(
      x1b, wt_w1, b1, nullptr, big, nullptr, 4096, 4096, 1024, 1024);
  // FFN2 + residual(x1b bf16): BN=128, BK=64, split-K=2, grid 32x8x2 -> partials res, qB
  gemm_bt<128, 64, false, false, true, true, true><<<dim3(32, 8, 2), 256, 0, stream>>>(
      big, wt_w2, b2, x1b, res, qB, 4096, 1024, 4096, 2048);
  // LN2 (combines partials) -> d_out
  ln_kernel<true, false, true><<<4096, 256, 0, stream>>>(res, qB, ln2g, ln2b,
                                                         (float*)d_out, nullptr);
}

// Round 12
// 223.097 us; speedup vs baseline: 1.2820x; 1.0479x over previous
//
#include <hip/hip_runtime.h>
#include <hip/hip_bf16.h>

typedef __bf16 bf16x8 __attribute__((ext_vector_type(8)));
typedef __bf16 bf16x4 __attribute__((ext_vector_type(4)));
typedef float f32x4 __attribute__((ext_vector_type(4)));

__device__ __forceinline__ void gload16(void* lds, const void* g) {
  __builtin_amdgcn_global_load_lds((const __attribute__((address_space(1))) void*)g,
                                   (__attribute__((address_space(3))) void*)lds, 16, 0, 0);
}

// ---------------- merged weight cast+transpose: 4 matrices, one launch ----------------
// in [R][C] fp32 -> out [C][R] bf16. Block ranges: qkv 3072, out 1024, w1 4096, w2 4096.
__global__ __launch_bounds__(256)
void transpose4(const float* __restrict__ s0, __bf16* __restrict__ d0,
                const float* __restrict__ s1, __bf16* __restrict__ d1,
                const float* __restrict__ s2, __bf16* __restrict__ d2,
                const float* __restrict__ s3, __bf16* __restrict__ d3)
{
  __shared__ __bf16 tile[32][33];
  int id = blockIdx.x;
  const float* in; __bf16* out; int R, C, bx, by;
  if (id < 3072)      { in = s0; out = d0; R = 1024; C = 3072; bx = id % 96;  by = id / 96; }
  else if (id < 4096) { id -= 3072; in = s1; out = d1; R = 1024; C = 1024; bx = id % 32;  by = id / 32; }
  else if (id < 8192) { id -= 4096; in = s2; out = d2; R = 1024; C = 4096; bx = id % 128; by = id / 128; }
  else                { id -= 8192; in = s3; out = d3; R = 4096; C = 1024; bx = id % 32;  by = id / 32; }
  const int bc = bx * 32, br = by * 32;
  const int lx = threadIdx.x & 31, ly = threadIdx.x >> 5;
#pragma unroll
  for (int p = 0; p < 4; ++p)
    tile[ly + p * 8][lx] = (__bf16)in[(size_t)(br + ly + p * 8) * C + bc + lx];
  __syncthreads();
#pragma unroll
  for (int p = 0; p < 4; ++p)
    out[(size_t)(bc + ly + p * 8) * R + br + lx] = tile[lx][ly + p * 8];
}

// ---------------- V transpose (bf16): qkv [B*S][3072] -> vtg [BH][64][2048] ----------------
__global__ __launch_bounds__(256)
void vtrans(const __bf16* __restrict__ qkv, __bf16* __restrict__ vtg)
{
  __shared__ __bf16 tile[32][33];
  const int sx = blockIdx.x * 32;
  const int dy = blockIdx.y * 32;
  const int z = blockIdx.z;
  const int b = z >> 4, h = z & 15;
  const int lx = threadIdx.x & 31, ly = threadIdx.x >> 5;
  const __bf16* src = qkv + (size_t)b * 2048 * 3072 + 2048 + h * 64;
#pragma unroll
  for (int p = 0; p < 4; ++p)
    tile[ly + p * 8][lx] = src[(size_t)(sx + ly + p * 8) * 3072 + dy + lx];
  __syncthreads();
  __bf16* dst = vtg + (size_t)z * 64 * 2048;
#pragma unroll
  for (int p = 0; p < 4; ++p)
    dst[(size_t)(dy + ly + p * 8) * 2048 + sx + lx] = tile[lx][ly + p * 8];
}

// ---------------- elementwise cast fp32 -> bf16 ----------------
__global__ __launch_bounds__(256)
void cast_bf16(const float* __restrict__ in, __bf16* __restrict__ out)
{
  const int i = (blockIdx.x * 256 + threadIdx.x) * 4;
  float4 v = *(const float4*)(in + i);
  out[i] = (__bf16)v.x; out[i + 1] = (__bf16)v.y;
  out[i + 2] = (__bf16)v.z; out[i + 3] = (__bf16)v.w;
}

// ========= 2-phase dbuf MFMA GEMM (proven structure), parametric BN/BK ====================
// RBF16: residual stream is bf16. SPLIT: blockIdx.z selects K-half; z=0 adds bias+resid;
// partials written in bf16 (LN2 combines).
template<int BN, int BK, bool OUT_BF16, bool RELU, bool RESID, bool RBF16, bool SPLIT>
__global__ __launch_bounds__(256)
void gemm_bt(const __bf16* __restrict__ A, const __bf16* __restrict__ Bt,
             const float* __restrict__ bias, const void* __restrict__ residv,
             void* __restrict__ C0v, void* __restrict__ C1v,
             int M, int N, int Kfull, int Ksub)
{
  constexpr int NW = BN / 32;          // n-frags per wave
  constexpr int CH = BK / 8;           // 16B chunks per row
  __shared__ __bf16 As[2][128 * BK];
  __shared__ __bf16 Bs[2][BN * BK];
  const int tid = threadIdx.x;
  const int wave = tid >> 6, lane = tid & 63;
  const int g = lane >> 4, l16 = lane & 15;
  const int row0 = blockIdx.x * 128, col0 = blockIdx.y * BN;
  const int z = SPLIT ? blockIdx.z : 0;
  const __bf16* Az = A + (size_t)z * Ksub;
  const __bf16* Bz = Bt + (size_t)z * Ksub;
  const int wr = wave >> 1, wc = wave & 1;
  f32x4 acc[4][NW] = {};
  const int nk = Ksub / BK;

  auto KEY = [](int row) -> int { return (BK == 64) ? (row & 7) : ((row >> 1) & 3); };

  auto STAGE = [&](int buf, int k0) {
#pragma unroll
    for (int r = 0; r < 128 * CH / 256; ++r) {
      const int seg = r * 256 + tid;
      const int row = seg / CH, cp = seg % CH;
      const int src = (cp ^ KEY(row)) * 8;
      gload16(&As[buf][(r * 256 + wave * 64) * 8], &Az[(size_t)(row0 + row) * Kfull + k0 + src]);
    }
#pragma unroll
    for (int r = 0; r < BN * CH / 256; ++r) {
      const int seg = r * 256 + tid;
      const int row = seg / CH, cp = seg % CH;
      const int src = (cp ^ KEY(row)) * 8;
      gload16(&Bs[buf][(r * 256 + wave * 64) * 8], &Bz[(size_t)(col0 + row) * Kfull + k0 + src]);
    }
  };

  STAGE(0, 0);
  __syncthreads();
  int cur = 0;
  for (int t = 0; t < nk; ++t) {
    if (t + 1 < nk) STAGE(cur ^ 1, (t + 1) * BK);
#pragma unroll
    for (int kk = 0; kk < BK / 32; ++kk) {
      bf16x8 af[4], bfr[NW];
#pragma unroll
      for (int m = 0; m < 4; ++m) {
        const int row = wr * 64 + m * 16 + l16;
        af[m] = *(const bf16x8*)&As[cur][row * BK + (((kk * 4 + g) ^ KEY(row)) << 3)];
      }
#pragma unroll
      for (int n = 0; n < NW; ++n) {
        const int row = wc * (BN / 2) + n * 16 + l16;
        bfr[n] = *(const bf16x8*)&Bs[cur][row * BK + (((kk * 4 + g) ^ KEY(row)) << 3)];
      }
#pragma unroll
      for (int m = 0; m < 4; ++m)
#pragma unroll
        for (int n = 0; n < NW; ++n)
          acc[m][n] = __builtin_amdgcn_mfma_f32_16x16x32_bf16(af[m], bfr[n], acc[m][n], 0, 0, 0);
    }
    __syncthreads();
    cur ^= 1;
  }
#pragma unroll
  for (int n = 0; n < NW; ++n) {
    const int col = col0 + wc * (BN / 2) + n * 16 + l16;
    float bv = 0.f;
    if (!SPLIT || z == 0) bv = bias[col];
#pragma unroll
    for (int m = 0; m < 4; ++m) {
      const int rrow = row0 + wr * 64 + m * 16 + g * 4;
#pragma unroll
      for (int r = 0; r < 4; ++r) {
        float v = acc[m][n][r] + bv;
        const size_t idx = (size_t)(rrow + r) * N + col;
        if (RESID && (!SPLIT || z == 0)) {
          if (RBF16) v += (float)((const __bf16*)residv)[idx];
          else       v += ((const float*)residv)[idx];
        }
        if (SPLIT) {
          ((__bf16*)(z ? C1v : C0v))[idx] = (__bf16)v;   // bf16 partial
        } else {
          if (RELU)  v = fmaxf(v, 0.f);
          if (OUT_BF16) ((__bf16*)C0v)[idx] = (__bf16)v;
          else          ((float*)C0v)[idx] = v;
        }
      }
    }
  }
}

// ---------------- flash attention (causal), swapped-QK^T, no-max softmax ------------------
// grid (32 bh, 32 y); qi = balanced permutation of y: every CU's 4 co-resident blocks
// have qi-set {31-j, 16+j, 15-j, j} summing to 66 kv-tiles (uniform), heavy first.
// 40 KB LDS -> 4 blocks/CU = 16 waves/CU.
__global__ __launch_bounds__(256)
void attn_fwd(const __bf16* __restrict__ qkv, const __bf16* __restrict__ vtg,
              __bf16* __restrict__ ctx)
{
  constexpr int S = 2048, H = 1024, W3 = 3 * H;
  __shared__ __bf16 Ks[2][64 * 64];
  __shared__ __bf16 Vt[2][64 * 64];
  __shared__ __bf16 Ps[4][16 * 64];
  const int tid = threadIdx.x, wave = tid >> 6, lane = tid & 63;
  const int g = lane >> 4, l16 = lane & 15;
  const int perm = ((l16 & 7) << 1) | (l16 >> 3);
  const int bh = blockIdx.x;
  const int y = blockIdx.y, j = y & 7, m = y >> 3;
  const int qi = (m == 0) ? (31 - j) : (m == 1) ? (16 + j) : (m == 2) ? (15 - j) : j;
  const int b = bh >> 4, h = bh & 15;
  const size_t base = (size_t)b * S * W3;
  const __bf16* Qg = qkv + base;
  const __bf16* Kg = qkv + base + H;
  const __bf16* Vg = vtg + (size_t)bh * 64 * S;

  auto STAGE_KV = [&](int buf, int kv0) {
#pragma unroll
    for (int r = 0; r < 2; ++r) {
      const int seg = r * 256 + tid;
      const int row = seg >> 3;
      const int ko = ((seg & 7) ^ (row & 7)) * 8;
      gload16(&Ks[buf][(r * 256 + wave * 64) * 8], &Kg[(size_t)(kv0 + row) * W3 + h * 64 + ko]);
      gload16(&Vt[buf][(r * 256 + wave * 64) * 8], &Vg[(size_t)row * S + kv0 + ko]);
    }
  };

  const int q0 = qi * 64;
  const int qrow = q0 + wave * 16 + l16;
  bf16x8 qa[2];
#pragma unroll
  for (int kk = 0; kk < 2; ++kk)
    qa[kk] = *(const bf16x8*)&Qg[(size_t)qrow * W3 + h * 64 + kk * 32 + g * 8];

  f32x4 o[4] = {};
  float lsum = 0.f;
  const int nT = qi + 1;

  STAGE_KV(0, 0);
  __syncthreads();
  int cur = 0;

  for (int t = 0; t < nT; ++t) {
    const int kv0 = t * 64;
    if (t + 1 < nT) STAGE_KV(cur ^ 1, kv0 + 64);

    f32x4 s[4] = {};
    __builtin_amdgcn_s_setprio(1);
#pragma unroll
    for (int kk = 0; kk < 2; ++kk) {
      bf16x8 kb[4];
#pragma unroll
      for (int n = 0; n < 4; ++n) {
        const int row = n * 16 + l16;
        kb[n] = *(const bf16x8*)&Ks[cur][row * 64 + ((kk * 32 + g * 8) ^ ((row & 7) << 3))];
      }
#pragma unroll
      for (int n = 0; n < 4; ++n)
        s[n] = __builtin_amdgcn_mfma_f32_16x16x32_bf16(kb[n], qa[kk], s[n], 0, 0, 0);
    }
    __builtin_amdgcn_s_setprio(0);

    const bool diag = (t == nT - 1);
#pragma unroll
    for (int n = 0; n < 4; ++n) {
      float lp[4];
#pragma unroll
      for (int r = 0; r < 4; ++r) {
        const int ka = kv0 + n * 16 + g * 4 + r;
        float p = exp2f(s[n][r] * 0.18033688f);
        if (diag && ka > qrow) p = 0.f;
        lp[r] = p;
        lsum += p;
      }
      bf16x4 pk;
      pk[0] = (__bf16)lp[0]; pk[1] = (__bf16)lp[1];
      pk[2] = (__bf16)lp[2]; pk[3] = (__bf16)lp[3];
      *(bf16x4*)&Ps[wave][l16 * 64 + (((4 * n + g) ^ perm) << 2)] = pk;
    }

    __builtin_amdgcn_s_setprio(1);
#pragma unroll
    for (int kk = 0; kk < 2; ++kk) {
      const int hb = 8 * kk + 2 * g;
      bf16x4 p0 = *(const bf16x4*)&Ps[wave][l16 * 64 + ((hb ^ perm) << 2)];
      bf16x4 p1 = *(const bf16x4*)&Ps[wave][l16 * 64 + (((hb + 1) ^ perm) << 2)];
      bf16x8 pa = __builtin_shufflevector(p0, p1, 0, 1, 2, 3, 4, 5, 6, 7);
      bf16x8 vb[4];
#pragma unroll
      for (int n2 = 0; n2 < 4; ++n2) {
        const int row = n2 * 16 + l16;
        vb[n2] = *(const bf16x8*)&Vt[cur][row * 64 + ((kk * 32 + g * 8) ^ ((row & 7) << 3))];
      }
#pragma unroll
      for (int n2 = 0; n2 < 4; ++n2)
        o[n2] = __builtin_amdgcn_mfma_f32_16x16x32_bf16(pa, vb[n2], o[n2], 0, 0, 0);
    }
    __builtin_amdgcn_s_setprio(0);
    __syncthreads();
    cur ^= 1;
  }

  lsum += __shfl_xor(lsum, 16);
  lsum += __shfl_xor(lsum, 32);
#pragma unroll
  for (int r = 0; r < 4; ++r) {
    const float den = __shfl(lsum, g * 4 + r);
    const float inv = 1.f / den;
    const int qr = q0 + wave * 16 + g * 4 + r;
#pragma unroll
    for (int n2 = 0; n2 < 4; ++n2) {
      const int d = n2 * 16 + l16;
      ctx[(size_t)(b * S + qr) * H + h * 64 + d] = (__bf16)(o[n2][r] * inv);
    }
  }
}

// ---------------- LayerNorm over rows of 1024, fp32 input -------------------------------
template<bool WRITE_F32, bool WRITE_BF16>
__global__ __launch_bounds__(256)
void ln_kernel(const float* __restrict__ in,
               const float* __restrict__ gw, const float* __restrict__ bw,
               float* __restrict__ outf, __bf16* __restrict__ outb)
{
  const int row = blockIdx.x, tid = threadIdx.x;
  float4 xv = ((const float4*)(in + (size_t)row * 1024))[tid];
  float s = xv.x + xv.y + xv.z + xv.w;
  float s2 = xv.x * xv.x + xv.y * xv.y + xv.z * xv.z + xv.w * xv.w;
#pragma unroll
  for (int off = 32; off; off >>= 1) { s += __shfl_xor(s, off); s2 += __shfl_xor(s2, off); }
  __shared__ float ps[8];
  if ((tid & 63) == 0) { ps[tid >> 6] = s; ps[4 + (tid >> 6)] = s2; }
  __syncthreads();
  s = ps[0] + ps[1] + ps[2] + ps[3];
  s2 = ps[4] + ps[5] + ps[6] + ps[7];
  const float mean = s * (1.f / 1024.f);
  const float var = s2 * (1.f / 1024.f) - mean * mean;
  const float rs = rsqrtf(var + 1e-5f);
  const float4 gv = ((const float4*)gw)[tid];
  const float4 bv = ((const float4*)bw)[tid];
  float4 y;
  y.x = (xv.x - mean) * rs * gv.x + bv.x;
  y.y = (xv.y - mean) * rs * gv.y + bv.y;
  y.z = (xv.z - mean) * rs * gv.z + bv.z;
  y.w = (xv.w - mean) * rs * gv.w + bv.w;
  if (WRITE_F32)
    ((float4*)(outf + (size_t)row * 1024))[tid] = y;
  if (WRITE_BF16) {
    __bf16* ob = outb + (size_t)row * 1024 + tid * 4;
    ob[0] = (__bf16)y.x; ob[1] = (__bf16)y.y; ob[2] = (__bf16)y.z; ob[3] = (__bf16)y.w;
  }
}

// ---------------- LayerNorm summing two bf16 partial inputs -> fp32 out ------------------
__global__ __launch_bounds__(256)
void ln2b_kernel(const __bf16* __restrict__ in, const __bf16* __restrict__ in2,
                 const float* __restrict__ gw, const float* __restrict__ bw,
                 float* __restrict__ outf)
{
  const int row = blockIdx.x, tid = threadIdx.x;
  const bf16x4 a = ((const bf16x4*)(in + (size_t)row * 1024))[tid];
  const bf16x4 b = ((const bf16x4*)(in2 + (size_t)row * 1024))[tid];
  float4 xv;
  xv.x = (float)a[0] + (float)b[0];
  xv.y = (float)a[1] + (float)b[1];
  xv.z = (float)a[2] + (float)b[2];
  xv.w = (float)a[3] + (float)b[3];
  float s = xv.x + xv.y + xv.z + xv.w;
  float s2 = xv.x * xv.x + xv.y * xv.y + xv.z * xv.z + xv.w * xv.w;
#pragma unroll
  for (int off = 32; off; off >>= 1) { s += __shfl_xor(s, off); s2 += __shfl_xor(s2, off); }
  __shared__ float ps[8];
  if ((tid & 63) == 0) { ps[tid >> 6] = s; ps[4 + (tid >> 6)] = s2; }
  __syncthreads();
  s = ps[0] + ps[1] + ps[2] + ps[3];
  s2 = ps[4] + ps[5] + ps[6] + ps[7];
  const float mean = s * (1.f / 1024.f);
  const float var = s2 * (1.f / 1024.f) - mean * mean;
  const float rs = rsqrtf(var + 1e-5f);
  const float4 gv = ((const float4*)gw)[tid];
  const float4 bv = ((const float4*)bw)[tid];
  float4 y;
  y.x = (xv.x - mean) * rs * gv.x + bv.x;
  y.y = (xv.y - mean) * rs * gv.y + bv.y;
  y.z = (xv.z - mean) * rs * gv.z + bv.z;
  y.w = (xv.w - mean) * rs * gv.w + bv.w;
  ((float4*)(outf + (size_t)row * 1024))[tid] = y;
}

extern "C" void kernel_launch(void* const* d_in, const int* in_sizes, int n_in,
                              void* d_out, int out_size, void* d_ws, size_t ws_size,
                              hipStream_t stream)
{
  (void)in_sizes; (void)n_in; (void)out_size; (void)ws_size;
  const float* x     = (const float*)d_in[0];
  const float* qkv_w = (const float*)d_in[2];
  const float* qkv_b = (const float*)d_in[3];
  const float* out_w = (const float*)d_in[4];
  const float* out_b = (const float*)d_in[5];
  const float* w1    = (const float*)d_in[6];
  const float* b1    = (const float*)d_in[7];
  const float* w2    = (const float*)d_in[8];
  const float* b2    = (const float*)d_in[9];
  const float* ln1g  = (const float*)d_in[10];
  const float* ln1b  = (const float*)d_in[11];
  const float* ln2g  = (const float*)d_in[12];
  const float* ln2b  = (const float*)d_in[13];

  char* ws = (char*)d_ws;
  __bf16* wt_qkv = (__bf16*)(ws + 0);          // [3072][1024]  dead after QKV
  __bf16* wt_out = (__bf16*)(ws + 6291456);    // [1024][1024]  dead after out-proj
  __bf16* wt_w1  = (__bf16*)(ws + 8388608);    // [4096][1024]  dead after FFN1
  __bf16* wt_w2  = (__bf16*)(ws + 16777216);   // [1024][4096]  live through FFN2
  __bf16* xb     = (__bf16*)(ws + 25165824);   // x bf16, then ctx
  __bf16* big    = (__bf16*)(ws + 33554432);   // qkv, then h1
  float*  res    = (float*)(ws + 67108864);    // vtg, then res1, then FFN2 bf16 partial z=0
  __bf16* x1b    = (__bf16*)(ws + 100663296);  // ln1 out bf16 (FFN1 A + FFN2 resid)
  __bf16* vtg    = (__bf16*)res;               // [32][64][2048] (dead after attn)
  __bf16* pz0    = (__bf16*)res;               // FFN2 partial z=0 (8MB, res1 dead post-LN1)
  __bf16* pz1    = (__bf16*)ws;                // FFN2 partial z=1 (8MB over dead wt_qkv+wt_out)

  transpose4<<<12288, 256, 0, stream>>>(qkv_w, wt_qkv, out_w, wt_out, w1, wt_w1, w2, wt_w2);
  cast_bf16<<<4096, 256, 0, stream>>>(x, xb);

  // QKV: BN=128, BK=64, grid 32x24
  gemm_bt<128, 64, true, false, false, false, false><<<dim3(32, 24), 256, 0, stream>>>(
      xb, wt_qkv, qkv_b, nullptr, big, nullptr, 4096, 3072, 1024, 1024);
  // V -> V^T per (b,h)
  vtrans<<<dim3(64, 2, 32), 256, 0, stream>>>(big, vtg);
  // attention -> ctx (reuses xb); 1024 balanced blocks, 4/CU
  attn_fwd<<<dim3(32, 32), 256, 0, stream>>>(big, vtg, xb);
  // out-proj + residual(x fp32) -> res fp32 ; BN=64, BK=64, grid 32x16
  gemm_bt<64, 64, false, false, true, false, false><<<dim3(32, 16), 256, 0, stream>>>(
      xb, wt_out, out_b, x, res, nullptr, 4096, 1024, 1024, 1024);
  // LN1 -> x1b bf16 only
  ln_kernel<false, true><<<4096, 256, 0, stream>>>(res, ln1g, ln1b, nullptr, x1b);
  // FFN1 + ReLU: BN=128, BK=64, grid 32x32 -> h1 bf16
  gemm_bt<128, 64, true, true, false, false, false><<<dim3(32, 32), 256, 0, stream>>>(
      x1b, wt_w1, b1, nullptr, big, nullptr, 4096, 4096, 1024, 1024);
  // FFN2 + residual(x1b bf16): split-K=2, grid 32x8x2 -> bf16 partials pz0, pz1
  gemm_bt<128, 64, false, false, true, true, true><<<dim3(32, 8, 2), 256, 0, stream>>>(
      big, wt_w2, b2, x1b, pz0, pz1, 4096, 1024, 4096, 2048);
  // LN2 (combines bf16 partials) -> d_out
  ln2b_kernel<<<4096, 256, 0, stream>>>(pz0, pz1, ln2g, ln2b, (float*)d_out);
}